// Round 1
// baseline (2598.928 us; speedup 1.0000x reference)
//
#include <hip/hip_runtime.h>

// GCN 2-layer: N=100k nodes, E=1.6M edges, IN=256, HID=64, OUT=40, fp32.
// h1s = (x@W1)*dinv[row]; acc1[dst] += h1s[src]; hrelu = relu(dinv*(acc1+h1s)+b1)
// h2s = (hrelu@W2)*dinv[row]; acc2[dst] += h2s[src]; out = dinv*(acc2+h2s)+b2

__device__ __forceinline__ float rl(float v, int l) {
  return __int_as_float(__builtin_amdgcn_readlane(__float_as_int(v), l));
}

__global__ void k_deg(const int* __restrict__ dst, float* __restrict__ deg, int E) {
  int e = blockIdx.x * blockDim.x + threadIdx.x;
  if (e < E) atomicAdd(&deg[dst[e]], 1.0f);
}

__global__ void k_dinv(float* __restrict__ deg, int N) {
  int i = blockIdx.x * blockDim.x + threadIdx.x;
  if (i < N) deg[i] = rsqrtf(deg[i] + 1.0f);  // +1 self-loop; deg>=1 always
}

// GEMM1: h1s[row][d] = dinv[row] * sum_k x[row][k]*W1[k][d]
// 4 waves/block, wave j owns k-chunk [j*64, j*64+64), W chunk in 64 VGPRs.
__global__ __launch_bounds__(256) void k_gemm1(const float* __restrict__ x,
    const float* __restrict__ W1, const float* __restrict__ dinv,
    float* __restrict__ h1s, int N) {
  const int lane = threadIdx.x & 63;
  const int j = threadIdx.x >> 6;
  float w[64];
#pragma unroll
  for (int t = 0; t < 64; ++t) w[t] = W1[(j * 64 + t) * 64 + lane];
  __shared__ float red[16][4][64];
  for (int rb = blockIdx.x * 16; rb < N; rb += gridDim.x * 16) {
    int rlim = N - rb; if (rlim > 16) rlim = 16;
    for (int r = 0; r < rlim; ++r) {
      int row = rb + r;
      float xv = x[(size_t)row * 256 + j * 64 + lane];  // coalesced 256B/wave
      float a0 = 0.f, a1 = 0.f, a2 = 0.f, a3 = 0.f;
#pragma unroll
      for (int t = 0; t < 16; ++t) {
        a0 += rl(xv, 4 * t + 0) * w[4 * t + 0];
        a1 += rl(xv, 4 * t + 1) * w[4 * t + 1];
        a2 += rl(xv, 4 * t + 2) * w[4 * t + 2];
        a3 += rl(xv, 4 * t + 3) * w[4 * t + 3];
      }
      red[r][j][lane] = (a0 + a1) + (a2 + a3);
    }
    __syncthreads();
    for (int o = threadIdx.x; o < 16 * 64; o += 256) {
      int r = o >> 6, d = o & 63, row = rb + r;
      if (r < rlim)
        h1s[(size_t)row * 64 + d] =
            (red[r][0][d] + red[r][1][d] + red[r][2][d] + red[r][3][d]) * dinv[row];
    }
    __syncthreads();
  }
}

// edge-parallel scatter: 16 threads/edge, 4 dims each (HID=64)
__global__ void k_agg1(const int* __restrict__ src, const int* __restrict__ dst,
    const float* __restrict__ h1s, float* __restrict__ acc1, int total) {
  int t = blockIdx.x * blockDim.x + threadIdx.x;
  if (t >= total) return;
  int e = t >> 4, q = t & 15;
  int s = src[e], d = dst[e];
  float4 v = reinterpret_cast<const float4*>(h1s + (size_t)s * 64)[q];
  float* a = acc1 + (size_t)d * 64 + q * 4;
  atomicAdd(a + 0, v.x); atomicAdd(a + 1, v.y);
  atomicAdd(a + 2, v.z); atomicAdd(a + 3, v.w);
}

// hrelu (in-place into h1s) = relu(dinv*(acc1 + h1s) + b1)
__global__ void k_final1(const float* __restrict__ acc1, const float* __restrict__ dinv,
    const float* __restrict__ b1, float* __restrict__ h1s, int total) {
  int t = blockIdx.x * blockDim.x + threadIdx.x;
  if (t >= total) return;
  int row = t >> 6, d = t & 63;
  float v = dinv[row] * (acc1[t] + h1s[t]) + b1[d];
  h1s[t] = v > 0.f ? v : 0.f;
}

// GEMM2: h2s[row][d] = dinv[row] * sum_k hrelu[row][k]*W2[k][d]; wave per row
__global__ __launch_bounds__(256) void k_gemm2(const float* __restrict__ hrelu,
    const float* __restrict__ W2, const float* __restrict__ dinv,
    float* __restrict__ h2s, int N) {
  const int lane = threadIdx.x & 63;
  const int wid = threadIdx.x >> 6;
  const int l2 = lane < 40 ? lane : 0;  // avoid OOB on W2 loads
  float w[64];
#pragma unroll
  for (int t = 0; t < 64; ++t) w[t] = W2[t * 40 + l2];
  for (int row = blockIdx.x * 4 + wid; row < N; row += gridDim.x * 4) {
    float xv = hrelu[(size_t)row * 64 + lane];
    float a0 = 0.f, a1 = 0.f, a2 = 0.f, a3 = 0.f;
#pragma unroll
    for (int t = 0; t < 16; ++t) {
      a0 += rl(xv, 4 * t + 0) * w[4 * t + 0];
      a1 += rl(xv, 4 * t + 1) * w[4 * t + 1];
      a2 += rl(xv, 4 * t + 2) * w[4 * t + 2];
      a3 += rl(xv, 4 * t + 3) * w[4 * t + 3];
    }
    if (lane < 40)
      h2s[(size_t)row * 40 + lane] = ((a0 + a1) + (a2 + a3)) * dinv[row];
  }
}

// 10 threads/edge, 4 dims each (OUT=40)
__global__ void k_agg2(const int* __restrict__ src, const int* __restrict__ dst,
    const float* __restrict__ h2s, float* __restrict__ acc2, int total) {
  int t = blockIdx.x * blockDim.x + threadIdx.x;
  if (t >= total) return;
  int e = t / 10, q = t - e * 10;
  int s = src[e], d = dst[e];
  float4 v = *reinterpret_cast<const float4*>(h2s + (size_t)s * 40 + q * 4);
  float* a = acc2 + (size_t)d * 40 + q * 4;
  atomicAdd(a + 0, v.x); atomicAdd(a + 1, v.y);
  atomicAdd(a + 2, v.z); atomicAdd(a + 3, v.w);
}

__global__ void k_final2(const float* __restrict__ acc2, const float* __restrict__ dinv,
    const float* __restrict__ b2, const float* __restrict__ h2s,
    float* __restrict__ out, int total) {
  int t = blockIdx.x * blockDim.x + threadIdx.x;
  if (t >= total) return;
  int row = t / 40, d = t - row * 40;
  out[t] = dinv[row] * (acc2[t] + h2s[t]) + b2[d];
}

extern "C" void kernel_launch(void* const* d_in, const int* in_sizes, int n_in,
                              void* d_out, int out_size, void* d_ws, size_t ws_size,
                              hipStream_t stream) {
  const float* x  = (const float*)d_in[0];
  const int*   ei = (const int*)d_in[1];
  const float* W1 = (const float*)d_in[2];
  const float* b1 = (const float*)d_in[3];
  const float* W2 = (const float*)d_in[4];
  const float* b2 = (const float*)d_in[5];
  float* out = (float*)d_out;

  const int N = in_sizes[0] / 256;
  const int E = in_sizes[1] / 2;
  const int* src = ei;       // edge_index[0]
  const int* dst = ei + E;   // edge_index[1]

  float* ws = (float*)d_ws;
  size_t nPad = ((size_t)N + 255) & ~(size_t)255;
  float* dinv = ws;                          // N (deg then dinv in-place)
  float* h1s  = ws + nPad;                   // N*64 (then hrelu in-place)
  float* acc1 = h1s + (size_t)N * 64;        // N*64
  float* acc2 = acc1 + (size_t)N * 64;       // N*40 (adjacent to acc1)
  float* h2s  = acc2 + (size_t)N * 40;       // N*40
  // total = nPad + N*232 floats ~ 83.6 MB

  hipMemsetAsync(dinv, 0, nPad * sizeof(float), stream);
  hipMemsetAsync(acc1, 0, (size_t)N * 104 * sizeof(float), stream);  // acc1+acc2

  k_deg <<<(E + 255) / 256, 256, 0, stream>>>(dst, dinv, E);
  k_dinv<<<(N + 255) / 256, 256, 0, stream>>>(dinv, N);

  k_gemm1<<<2048, 256, 0, stream>>>(x, W1, dinv, h1s, N);

  int tot1 = E * 16;
  k_agg1<<<(tot1 + 255) / 256, 256, 0, stream>>>(src, dst, h1s, acc1, tot1);
  int nt1 = N * 64;
  k_final1<<<(nt1 + 255) / 256, 256, 0, stream>>>(acc1, dinv, b1, h1s, nt1);

  k_gemm2<<<2048, 256, 0, stream>>>(h1s, W2, dinv, h2s, N);

  int tot2 = E * 10;
  k_agg2<<<(tot2 + 255) / 256, 256, 0, stream>>>(src, dst, h2s, acc2, tot2);
  int nt2 = N * 40;
  k_final2<<<(nt2 + 255) / 256, 256, 0, stream>>>(acc2, dinv, b2, h2s, out, nt2);
}

// Round 2
// 521.466 us; speedup vs baseline: 4.9839x; 4.9839x over previous
//
#include <hip/hip_runtime.h>

// GCN 2-layer, fp32. CSR-gather aggregation (no fp32 atomics).
// h1s = (x@W1)*dinv[row]; hrelu[d] = relu(dinv[d]*(sum_in h1s[src] + h1s[d]) + b1)
// h2s = (hrelu@W2)*dinv[row]; out[d] = dinv[d]*(sum_in h2s[src] + h2s[d]) + b2

__device__ __forceinline__ float rl(float v, int l) {
  return __int_as_float(__builtin_amdgcn_readlane(__float_as_int(v), l));
}

// ---- CSR build ----
__global__ void k_count(const int* __restrict__ dst, int* __restrict__ deg, int E) {
  int e = blockIdx.x * blockDim.x + threadIdx.x;
  if (e < E) atomicAdd(&deg[dst[e]], 1);
}

__global__ void k_dinv(const int* __restrict__ deg, float* __restrict__ dinv, int N) {
  int i = blockIdx.x * blockDim.x + threadIdx.x;
  if (i < N) dinv[i] = rsqrtf((float)deg[i] + 1.0f);  // +1 self-loop
}

__global__ void k_blocksum(const int* __restrict__ deg, int* __restrict__ bsum, int N) {
  __shared__ int s[256];
  int t = threadIdx.x, i = blockIdx.x * 256 + t;
  s[t] = (i < N) ? deg[i] : 0;
  __syncthreads();
  for (int off = 128; off; off >>= 1) {
    if (t < off) s[t] += s[t + off];
    __syncthreads();
  }
  if (t == 0) bsum[blockIdx.x] = s[0];
}

__global__ void k_scanb(int* __restrict__ bsum, int nb) {  // 1 block, 512 thr; nb<=512
  __shared__ int s[512];
  int t = threadIdx.x;
  s[t] = (t < nb) ? bsum[t] : 0;
  __syncthreads();
  for (int off = 1; off < 512; off <<= 1) {
    int v = (t >= off) ? s[t - off] : 0;
    __syncthreads();
    s[t] += v;
    __syncthreads();
  }
  if (t < nb) bsum[t] = t ? s[t - 1] : 0;  // exclusive
}

__global__ void k_scan3(const int* __restrict__ deg, const int* __restrict__ bsum,
                        int* __restrict__ rowptr, int* __restrict__ cursor, int N, int E) {
  __shared__ int s[256];
  int t = threadIdx.x, i = blockIdx.x * 256 + t;
  s[t] = (i < N) ? deg[i] : 0;
  __syncthreads();
  for (int off = 1; off < 256; off <<= 1) {
    int v = (t >= off) ? s[t - off] : 0;
    __syncthreads();
    s[t] += v;
    __syncthreads();
  }
  if (i < N) {
    int ex = bsum[blockIdx.x] + (t ? s[t - 1] : 0);
    rowptr[i] = ex;
    cursor[i] = ex;
    if (i == N - 1) rowptr[N] = E;
  }
}

__global__ void k_scatter(const int* __restrict__ src, const int* __restrict__ dst,
                          int* __restrict__ cursor, int* __restrict__ csr, int E) {
  int e = blockIdx.x * blockDim.x + threadIdx.x;
  if (e >= E) return;
  int pos = atomicAdd(&cursor[dst[e]], 1);
  csr[pos] = src[e];
}

// ---- GEMM1: h1s[row][d] = dinv[row] * sum_k x[row][k]*W1[k][d] ----
__global__ __launch_bounds__(256) void k_gemm1(const float* __restrict__ x,
    const float* __restrict__ W1, const float* __restrict__ dinv,
    float* __restrict__ h1s, int N) {
  const int lane = threadIdx.x & 63;
  const int j = threadIdx.x >> 6;
  float w[64];
#pragma unroll
  for (int t = 0; t < 64; ++t) w[t] = W1[(j * 64 + t) * 64 + lane];
  __shared__ float red[16][4][64];
  for (int rb = blockIdx.x * 16; rb < N; rb += gridDim.x * 16) {
    int rlim = N - rb; if (rlim > 16) rlim = 16;
    for (int r = 0; r < rlim; ++r) {
      int row = rb + r;
      float xv = x[(size_t)row * 256 + j * 64 + lane];
      float a0 = 0.f, a1 = 0.f, a2 = 0.f, a3 = 0.f;
#pragma unroll
      for (int t = 0; t < 16; ++t) {
        a0 += rl(xv, 4 * t + 0) * w[4 * t + 0];
        a1 += rl(xv, 4 * t + 1) * w[4 * t + 1];
        a2 += rl(xv, 4 * t + 2) * w[4 * t + 2];
        a3 += rl(xv, 4 * t + 3) * w[4 * t + 3];
      }
      red[r][j][lane] = (a0 + a1) + (a2 + a3);
    }
    __syncthreads();
    for (int o = threadIdx.x; o < 16 * 64; o += 256) {
      int r = o >> 6, d = o & 63, row = rb + r;
      if (r < rlim)
        h1s[(size_t)row * 64 + d] =
            (red[r][0][d] + red[r][1][d] + red[r][2][d] + red[r][3][d]) * dinv[row];
    }
    __syncthreads();
  }
}

// ---- agg1 fused: wave per node, lane = dim (HID=64) ----
__global__ __launch_bounds__(256) void k_agg1f(const float* __restrict__ h1s,
    const int* __restrict__ rowptr, const int* __restrict__ csr,
    const float* __restrict__ dinv, const float* __restrict__ b1,
    float* __restrict__ hrelu, int N) {
  const int lane = threadIdx.x & 63;
  const int row = blockIdx.x * 4 + (threadIdx.x >> 6);
  if (row >= N) return;
  const int beg = rowptr[row], end = rowptr[row + 1];
  float acc = h1s[(size_t)row * 64 + lane];  // self term (pre-scaled by dinv[row])
  for (int b = beg; b < end; b += 64) {
    int m = end - b; if (m > 64) m = 64;
    int idx = (lane < m) ? csr[b + lane] : 0;
    for (int t = 0; t < m; ++t) {
      int s = __builtin_amdgcn_readlane(idx, t);
      acc += h1s[(size_t)s * 64 + lane];
    }
  }
  float v = dinv[row] * acc + b1[lane];
  hrelu[(size_t)row * 64 + lane] = v > 0.f ? v : 0.f;
}

// ---- GEMM2: h2s[row][d] = dinv[row] * sum_k hrelu[row][k]*W2[k][d] ----
__global__ __launch_bounds__(256) void k_gemm2(const float* __restrict__ hrelu,
    const float* __restrict__ W2, const float* __restrict__ dinv,
    float* __restrict__ h2s, int N) {
  const int lane = threadIdx.x & 63;
  const int wid = threadIdx.x >> 6;
  const int l2 = lane < 40 ? lane : 0;
  float w[64];
#pragma unroll
  for (int t = 0; t < 64; ++t) w[t] = W2[t * 40 + l2];
  for (int row = blockIdx.x * 4 + wid; row < N; row += gridDim.x * 4) {
    float xv = hrelu[(size_t)row * 64 + lane];
    float a0 = 0.f, a1 = 0.f, a2 = 0.f, a3 = 0.f;
#pragma unroll
    for (int t = 0; t < 16; ++t) {
      a0 += rl(xv, 4 * t + 0) * w[4 * t + 0];
      a1 += rl(xv, 4 * t + 1) * w[4 * t + 1];
      a2 += rl(xv, 4 * t + 2) * w[4 * t + 2];
      a3 += rl(xv, 4 * t + 3) * w[4 * t + 3];
    }
    if (lane < 40)
      h2s[(size_t)row * 40 + lane] = ((a0 + a1) + (a2 + a3)) * dinv[row];
  }
}

// ---- agg2 fused: wave per node, lanes 0..39 = dims (OUT=40) ----
__global__ __launch_bounds__(256) void k_agg2f(const float* __restrict__ h2s,
    const int* __restrict__ rowptr, const int* __restrict__ csr,
    const float* __restrict__ dinv, const float* __restrict__ b2,
    float* __restrict__ out, int N) {
  const int lane = threadIdx.x & 63;
  const int row = blockIdx.x * 4 + (threadIdx.x >> 6);
  if (row >= N) return;
  const int dl = lane < 40 ? lane : 39;  // clamp: lanes 40..63 duplicate-load
  const int beg = rowptr[row], end = rowptr[row + 1];
  float acc = h2s[(size_t)row * 40 + dl];  // self term
  for (int b = beg; b < end; b += 64) {
    int m = end - b; if (m > 64) m = 64;
    int idx = (lane < m) ? csr[b + lane] : 0;
    for (int t = 0; t < m; ++t) {
      int s = __builtin_amdgcn_readlane(idx, t);
      acc += h2s[(size_t)s * 40 + dl];
    }
  }
  if (lane < 40)
    out[(size_t)row * 40 + lane] = dinv[row] * acc + b2[lane];
}

extern "C" void kernel_launch(void* const* d_in, const int* in_sizes, int n_in,
                              void* d_out, int out_size, void* d_ws, size_t ws_size,
                              hipStream_t stream) {
  const float* x  = (const float*)d_in[0];
  const int*   ei = (const int*)d_in[1];
  const float* W1 = (const float*)d_in[2];
  const float* b1 = (const float*)d_in[3];
  const float* W2 = (const float*)d_in[4];
  const float* b2 = (const float*)d_in[5];
  float* out = (float*)d_out;

  const int N = in_sizes[0] / 256;
  const int E = in_sizes[1] / 2;
  const int* src = ei;       // edge_index[0]
  const int* dst = ei + E;   // edge_index[1]

  // workspace layout (4B units)
  int* deg    = (int*)d_ws;             // N
  int* rowptr = deg + N;                // N+1
  int* cursor = rowptr + N + 1;         // N
  int* bsum   = cursor + N;             // 1024
  int* csr    = bsum + 1024;            // E
  float* dinv = (float*)(csr + E);      // N
  float* h1s  = dinv + N;               // N*64
  float* hrelu= h1s + (size_t)N * 64;   // N*64
  float* h2s  = hrelu + (size_t)N * 64; // N*40
  // ~75.3 MB total

  const int nb = (N + 255) / 256;       // 391 scan blocks (<=512)

  hipMemsetAsync(deg, 0, (size_t)N * sizeof(int), stream);

  k_count   <<<(E + 255) / 256, 256, 0, stream>>>(dst, deg, E);
  k_dinv    <<<nb, 256, 0, stream>>>(deg, dinv, N);
  k_blocksum<<<nb, 256, 0, stream>>>(deg, bsum, N);
  k_scanb   <<<1, 512, 0, stream>>>(bsum, nb);
  k_scan3   <<<nb, 256, 0, stream>>>(deg, bsum, rowptr, cursor, N, E);
  k_scatter <<<(E + 255) / 256, 256, 0, stream>>>(src, dst, cursor, csr, E);

  k_gemm1<<<2048, 256, 0, stream>>>(x, W1, dinv, h1s, N);
  k_agg1f<<<(N + 3) / 4, 256, 0, stream>>>(h1s, rowptr, csr, dinv, b1, hrelu, N);
  k_gemm2<<<2048, 256, 0, stream>>>(hrelu, W2, dinv, h2s, N);
  k_agg2f<<<(N + 3) / 4, 256, 0, stream>>>(h2s, rowptr, csr, dinv, b2, out, N);
}

// Round 3
// 371.220 us; speedup vs baseline: 7.0010x; 1.4047x over previous
//
#include <hip/hip_runtime.h>

// GCN 2-layer, fp32. CSR built with NO global atomics (bucket sort + LDS counting sort).
// h1s = (x@W1)*dinv[row]; hrelu = relu(dinv*(gather-sum h1s[src] + h1s[row]) + b1)
// h2s = (hrelu@W2)*dinv[row]; out = dinv*(gather-sum h2s[src] + h2s[row]) + b2

#define CHUNK 4096   // edges per hist/scatter block
#define BSH   8      // bucket = dst >> 8 (256 nodes per bucket)

__device__ __forceinline__ float rl(float v, int l) {
  return __int_as_float(__builtin_amdgcn_readlane(__float_as_int(v), l));
}

// ---- 1. per-chunk bucket histogram (LDS atomics only) ----
__global__ __launch_bounds__(256) void k_hist(const int* __restrict__ dst,
    int* __restrict__ hist, int E, int nbuck) {
  __shared__ int h[512];
  for (int i = threadIdx.x; i < nbuck; i += 256) h[i] = 0;
  __syncthreads();
  int base = blockIdx.x * CHUNK;
  int lim = base + CHUNK < E ? base + CHUNK : E;
  for (int i = base + threadIdx.x; i < lim; i += 256)
    atomicAdd(&h[dst[i] >> BSH], 1);
  __syncthreads();
  for (int i = threadIdx.x; i < nbuck; i += 256)
    hist[(size_t)blockIdx.x * nbuck + i] = h[i];
}

// ---- 2. per-bucket exclusive scan over chunks (in place); column totals ----
__global__ __launch_bounds__(256) void k_scanA(int* __restrict__ hist,
    int* __restrict__ colsum, int nchunk, int nbuck) {
  __shared__ int s[512];
  int b = blockIdx.x, t = threadIdx.x;
  s[t]       = (t < nchunk)       ? hist[(size_t)t * nbuck + b]         : 0;
  s[t + 256] = (t + 256 < nchunk) ? hist[(size_t)(t + 256) * nbuck + b] : 0;
  __syncthreads();
  for (int off = 1; off < 512; off <<= 1) {
    int a0 = (t >= off) ? s[t - off] : 0;
    int a1 = (t + 256 >= off) ? s[t + 256 - off] : 0;
    __syncthreads();
    s[t] += a0; s[t + 256] += a1;
    __syncthreads();
  }
  if (t < nchunk) hist[(size_t)t * nbuck + b] = t ? s[t - 1] : 0;
  if (t + 256 < nchunk) hist[(size_t)(t + 256) * nbuck + b] = s[t + 255];
  if (t == 0) colsum[b] = s[nchunk - 1];
}

// ---- 3. scan bucket totals -> bucket starts ----
__global__ __launch_bounds__(512) void k_scanB(const int* __restrict__ colsum,
    int* __restrict__ bstart, int nbuck, int E) {
  __shared__ int s[512];
  int t = threadIdx.x;
  s[t] = (t < nbuck) ? colsum[t] : 0;
  __syncthreads();
  for (int off = 1; off < 512; off <<= 1) {
    int a = (t >= off) ? s[t - off] : 0;
    __syncthreads();
    s[t] += a;
    __syncthreads();
  }
  if (t < nbuck) bstart[t] = t ? s[t - 1] : 0;
  if (t == 0) bstart[nbuck] = E;
}

// ---- 4. scatter edges into bucket-sorted ebuf (LDS cursors only) ----
__global__ __launch_bounds__(256) void k_scatter2(const int* __restrict__ src,
    const int* __restrict__ dst, const int* __restrict__ hist,
    const int* __restrict__ bstart, int2* __restrict__ ebuf, int E, int nbuck) {
  __shared__ int cur[512];
  for (int i = threadIdx.x; i < nbuck; i += 256)
    cur[i] = bstart[i] + hist[(size_t)blockIdx.x * nbuck + i];
  __syncthreads();
  int base = blockIdx.x * CHUNK;
  int lim = base + CHUNK < E ? base + CHUNK : E;
  for (int i = base + threadIdx.x; i < lim; i += 256) {
    int d = dst[i];
    int pos = atomicAdd(&cur[d >> BSH], 1);
    ebuf[pos] = make_int2(src[i], d);
  }
}

// ---- 5. per-bucket LDS counting sort -> csr, rowptr, dinv ----
__global__ __launch_bounds__(256) void k_csr(const int2* __restrict__ ebuf,
    const int* __restrict__ bstart, int* __restrict__ csr, int* __restrict__ rowptr,
    float* __restrict__ dinv, int N, int E, int nbuck) {
  int b = blockIdx.x, t = threadIdx.x;
  int beg = bstart[b], end = bstart[b + 1];
  __shared__ int s[256];
  __shared__ int cur[256];
  s[t] = 0;
  __syncthreads();
  for (int i = beg + t; i < end; i += 256)
    atomicAdd(&s[ebuf[i].y & 255], 1);
  __syncthreads();
  int cnt = s[t];
  for (int off = 1; off < 256; off <<= 1) {  // inclusive scan of counts
    int a = (t >= off) ? s[t - off] : 0;
    __syncthreads();
    s[t] += a;
    __syncthreads();
  }
  int ex = t ? s[t - 1] : 0;  // exclusive
  cur[t] = beg + ex;
  int node = (b << BSH) + t;
  if (node < N) {
    rowptr[node] = beg + ex;
    dinv[node] = rsqrtf((float)cnt + 1.0f);  // +1 self-loop
  }
  if (b == 0 && t == 0) rowptr[N] = E;
  __syncthreads();
  for (int i = beg + t; i < end; i += 256) {
    int2 e = ebuf[i];
    int pos = atomicAdd(&cur[e.y & 255], 1);
    csr[pos] = e.x;
  }
}

// ---- GEMM1: h1s[row][d] = dinv[row] * sum_k x[row][k]*W1[k][d] ----
__global__ __launch_bounds__(256) void k_gemm1(const float* __restrict__ x,
    const float* __restrict__ W1, const float* __restrict__ dinv,
    float* __restrict__ h1s, int N) {
  const int lane = threadIdx.x & 63;
  const int j = threadIdx.x >> 6;
  float w[64];
#pragma unroll
  for (int t = 0; t < 64; ++t) w[t] = W1[(j * 64 + t) * 64 + lane];
  __shared__ float red[16][4][64];
  for (int rb = blockIdx.x * 16; rb < N; rb += gridDim.x * 16) {
    int rlim = N - rb; if (rlim > 16) rlim = 16;
    for (int r = 0; r < rlim; ++r) {
      int row = rb + r;
      float xv = x[(size_t)row * 256 + j * 64 + lane];
      float a0 = 0.f, a1 = 0.f, a2 = 0.f, a3 = 0.f;
#pragma unroll
      for (int t = 0; t < 16; ++t) {
        a0 += rl(xv, 4 * t + 0) * w[4 * t + 0];
        a1 += rl(xv, 4 * t + 1) * w[4 * t + 1];
        a2 += rl(xv, 4 * t + 2) * w[4 * t + 2];
        a3 += rl(xv, 4 * t + 3) * w[4 * t + 3];
      }
      red[r][j][lane] = (a0 + a1) + (a2 + a3);
    }
    __syncthreads();
    for (int o = threadIdx.x; o < 16 * 64; o += 256) {
      int r = o >> 6, d = o & 63, row = rb + r;
      if (r < rlim)
        h1s[(size_t)row * 64 + d] =
            (red[r][0][d] + red[r][1][d] + red[r][2][d] + red[r][3][d]) * dinv[row];
    }
    __syncthreads();
  }
}

// ---- agg1 fused: wave per node, lane = dim (HID=64) ----
__global__ __launch_bounds__(256) void k_agg1f(const float* __restrict__ h1s,
    const int* __restrict__ rowptr, const int* __restrict__ csr,
    const float* __restrict__ dinv, const float* __restrict__ b1,
    float* __restrict__ hrelu, int N) {
  const int lane = threadIdx.x & 63;
  const int row = blockIdx.x * 4 + (threadIdx.x >> 6);
  if (row >= N) return;
  const int beg = rowptr[row], end = rowptr[row + 1];
  float acc = h1s[(size_t)row * 64 + lane];  // self term (pre-scaled by dinv[row])
  for (int b = beg; b < end; b += 64) {
    int m = end - b; if (m > 64) m = 64;
    int idx = (lane < m) ? csr[b + lane] : 0;
    for (int t = 0; t < m; ++t) {
      int s = __builtin_amdgcn_readlane(idx, t);
      acc += h1s[(size_t)s * 64 + lane];
    }
  }
  float v = dinv[row] * acc + b1[lane];
  hrelu[(size_t)row * 64 + lane] = v > 0.f ? v : 0.f;
}

// ---- GEMM2: h2s[row][d] = dinv[row] * sum_k hrelu[row][k]*W2[k][d] ----
__global__ __launch_bounds__(256) void k_gemm2(const float* __restrict__ hrelu,
    const float* __restrict__ W2, const float* __restrict__ dinv,
    float* __restrict__ h2s, int N) {
  const int lane = threadIdx.x & 63;
  const int wid = threadIdx.x >> 6;
  const int l2 = lane < 40 ? lane : 0;
  float w[64];
#pragma unroll
  for (int t = 0; t < 64; ++t) w[t] = W2[t * 40 + l2];
  for (int row = blockIdx.x * 4 + wid; row < N; row += gridDim.x * 4) {
    float xv = hrelu[(size_t)row * 64 + lane];
    float a0 = 0.f, a1 = 0.f, a2 = 0.f, a3 = 0.f;
#pragma unroll
    for (int t = 0; t < 16; ++t) {
      a0 += rl(xv, 4 * t + 0) * w[4 * t + 0];
      a1 += rl(xv, 4 * t + 1) * w[4 * t + 1];
      a2 += rl(xv, 4 * t + 2) * w[4 * t + 2];
      a3 += rl(xv, 4 * t + 3) * w[4 * t + 3];
    }
    if (lane < 40)
      h2s[(size_t)row * 40 + lane] = ((a0 + a1) + (a2 + a3)) * dinv[row];
  }
}

// ---- agg2 fused: wave per node, lanes 0..39 = dims (OUT=40) ----
__global__ __launch_bounds__(256) void k_agg2f(const float* __restrict__ h2s,
    const int* __restrict__ rowptr, const int* __restrict__ csr,
    const float* __restrict__ dinv, const float* __restrict__ b2,
    float* __restrict__ out, int N) {
  const int lane = threadIdx.x & 63;
  const int row = blockIdx.x * 4 + (threadIdx.x >> 6);
  if (row >= N) return;
  const int dl = lane < 40 ? lane : 39;
  const int beg = rowptr[row], end = rowptr[row + 1];
  float acc = h2s[(size_t)row * 40 + dl];  // self term
  for (int b = beg; b < end; b += 64) {
    int m = end - b; if (m > 64) m = 64;
    int idx = (lane < m) ? csr[b + lane] : 0;
    for (int t = 0; t < m; ++t) {
      int s = __builtin_amdgcn_readlane(idx, t);
      acc += h2s[(size_t)s * 40 + dl];
    }
  }
  if (lane < 40)
    out[(size_t)row * 40 + lane] = dinv[row] * acc + b2[lane];
}

extern "C" void kernel_launch(void* const* d_in, const int* in_sizes, int n_in,
                              void* d_out, int out_size, void* d_ws, size_t ws_size,
                              hipStream_t stream) {
  const float* x  = (const float*)d_in[0];
  const int*   ei = (const int*)d_in[1];
  const float* W1 = (const float*)d_in[2];
  const float* b1 = (const float*)d_in[3];
  const float* W2 = (const float*)d_in[4];
  const float* b2 = (const float*)d_in[5];
  float* out = (float*)d_out;

  const int N = in_sizes[0] / 256;
  const int E = in_sizes[1] / 2;
  const int* src = ei;       // edge_index[0]
  const int* dst = ei + E;   // edge_index[1]

  const int nchunk = (E + CHUNK - 1) / CHUNK;   // 391
  const int nbuck  = (N + 255) >> BSH;          // 391 (<=512 assumed)

  // workspace layout (4B units, 8B-aligned sections)
  int* ws = (int*)d_ws;
  size_t o = 0;
  int* hist    = ws + o; o += ((size_t)nchunk * nbuck + 1) & ~(size_t)1;
  int* colsum  = ws + o; o += 512;
  int* bstart  = ws + o; o += ((size_t)nbuck + 1 + 1) & ~(size_t)1;
  int* rowptr  = ws + o; o += ((size_t)N + 2) & ~(size_t)1;
  float* dinv  = (float*)(ws + o); o += (size_t)N;
  int* csr     = ws + o; o += (size_t)E;
  float* h1s   = (float*)(ws + o); o += (size_t)N * 64;
  float* hrelu = (float*)(ws + o); o += (size_t)N * 64;
  // ebuf (E int2) and h2s (N*40 f32) never live simultaneously: alias
  size_t tail = (o + 1) & ~(size_t)1;
  int2*  ebuf = (int2*)(ws + tail);
  float* h2s  = (float*)(ws + tail);

  k_hist    <<<nchunk, 256, 0, stream>>>(dst, hist, E, nbuck);
  k_scanA   <<<nbuck, 256, 0, stream>>>(hist, colsum, nchunk, nbuck);
  k_scanB   <<<1, 512, 0, stream>>>(colsum, bstart, nbuck, E);
  k_scatter2<<<nchunk, 256, 0, stream>>>(src, dst, hist, bstart, ebuf, E, nbuck);
  k_csr     <<<nbuck, 256, 0, stream>>>(ebuf, bstart, csr, rowptr, dinv, N, E, nbuck);

  k_gemm1<<<2048, 256, 0, stream>>>(x, W1, dinv, h1s, N);
  k_agg1f<<<(N + 3) / 4, 256, 0, stream>>>(h1s, rowptr, csr, dinv, b1, hrelu, N);
  k_gemm2<<<2048, 256, 0, stream>>>(hrelu, W2, dinv, h2s, N);
  k_agg2f<<<(N + 3) / 4, 256, 0, stream>>>(h2s, rowptr, csr, dinv, b2, out, N);
}

// Round 4
// 271.803 us; speedup vs baseline: 9.5618x; 1.3658x over previous
//
#include <hip/hip_runtime.h>

// GCN 2-layer, fp32. CSR via bucket sort (no global atomics); tiled vector GEMM1;
// quarter-wave float4 gather aggregation.
// h1s = (x@W1)*dinv[row]; hrelu = relu(dinv*(gather-sum h1s[src] + h1s[row]) + b1)
// h2s = (hrelu@W2)*dinv[row]; out = dinv*(gather-sum h2s[src] + h2s[row]) + b2

#define CHUNK 4096   // edges per hist/scatter block
#define BSH   8      // bucket = dst >> 8 (256 nodes per bucket)

__device__ __forceinline__ float rl(float v, int l) {
  return __int_as_float(__builtin_amdgcn_readlane(__float_as_int(v), l));
}

// ---- 1. per-chunk bucket histogram (LDS atomics only) ----
__global__ __launch_bounds__(256) void k_hist(const int* __restrict__ dst,
    int* __restrict__ hist, int E, int nbuck) {
  __shared__ int h[512];
  for (int i = threadIdx.x; i < nbuck; i += 256) h[i] = 0;
  __syncthreads();
  int base = blockIdx.x * CHUNK;
  int lim = base + CHUNK < E ? base + CHUNK : E;
  for (int i = base + threadIdx.x; i < lim; i += 256)
    atomicAdd(&h[dst[i] >> BSH], 1);
  __syncthreads();
  for (int i = threadIdx.x; i < nbuck; i += 256)
    hist[(size_t)blockIdx.x * nbuck + i] = h[i];
}

// ---- 2. per-bucket exclusive scan over chunks (in place); column totals ----
__global__ __launch_bounds__(256) void k_scanA(int* __restrict__ hist,
    int* __restrict__ colsum, int nchunk, int nbuck) {
  __shared__ int s[512];
  int b = blockIdx.x, t = threadIdx.x;
  s[t]       = (t < nchunk)       ? hist[(size_t)t * nbuck + b]         : 0;
  s[t + 256] = (t + 256 < nchunk) ? hist[(size_t)(t + 256) * nbuck + b] : 0;
  __syncthreads();
  for (int off = 1; off < 512; off <<= 1) {
    int a0 = (t >= off) ? s[t - off] : 0;
    int a1 = (t + 256 >= off) ? s[t + 256 - off] : 0;
    __syncthreads();
    s[t] += a0; s[t + 256] += a1;
    __syncthreads();
  }
  if (t < nchunk) hist[(size_t)t * nbuck + b] = t ? s[t - 1] : 0;
  if (t + 256 < nchunk) hist[(size_t)(t + 256) * nbuck + b] = s[t + 255];
  if (t == 0) colsum[b] = s[nchunk - 1];
}

// ---- 3. scan bucket totals -> bucket starts ----
__global__ __launch_bounds__(512) void k_scanB(const int* __restrict__ colsum,
    int* __restrict__ bstart, int nbuck, int E) {
  __shared__ int s[512];
  int t = threadIdx.x;
  s[t] = (t < nbuck) ? colsum[t] : 0;
  __syncthreads();
  for (int off = 1; off < 512; off <<= 1) {
    int a = (t >= off) ? s[t - off] : 0;
    __syncthreads();
    s[t] += a;
    __syncthreads();
  }
  if (t < nbuck) bstart[t] = t ? s[t - 1] : 0;
  if (t == 0) bstart[nbuck] = E;
}

// ---- 4. scatter edges into bucket-sorted ebuf (LDS cursors only) ----
__global__ __launch_bounds__(256) void k_scatter2(const int* __restrict__ src,
    const int* __restrict__ dst, const int* __restrict__ hist,
    const int* __restrict__ bstart, int2* __restrict__ ebuf, int E, int nbuck) {
  __shared__ int cur[512];
  for (int i = threadIdx.x; i < nbuck; i += 256)
    cur[i] = bstart[i] + hist[(size_t)blockIdx.x * nbuck + i];
  __syncthreads();
  int base = blockIdx.x * CHUNK;
  int lim = base + CHUNK < E ? base + CHUNK : E;
  for (int i = base + threadIdx.x; i < lim; i += 256) {
    int d = dst[i];
    int pos = atomicAdd(&cur[d >> BSH], 1);
    ebuf[pos] = make_int2(src[i], d);
  }
}

// ---- 5. per-bucket LDS counting sort -> csr, rowptr, dinv ----
__global__ __launch_bounds__(256) void k_csr(const int2* __restrict__ ebuf,
    const int* __restrict__ bstart, int* __restrict__ csr, int* __restrict__ rowptr,
    float* __restrict__ dinv, int N, int E, int nbuck) {
  int b = blockIdx.x, t = threadIdx.x;
  int beg = bstart[b], end = bstart[b + 1];
  __shared__ int s[256];
  __shared__ int cur[256];
  s[t] = 0;
  __syncthreads();
  for (int i = beg + t; i < end; i += 256)
    atomicAdd(&s[ebuf[i].y & 255], 1);
  __syncthreads();
  int cnt = s[t];
  for (int off = 1; off < 256; off <<= 1) {  // inclusive scan
    int a = (t >= off) ? s[t - off] : 0;
    __syncthreads();
    s[t] += a;
    __syncthreads();
  }
  int ex = t ? s[t - 1] : 0;
  cur[t] = beg + ex;
  int node = (b << BSH) + t;
  if (node < N) {
    rowptr[node] = beg + ex;
    dinv[node] = rsqrtf((float)cnt + 1.0f);  // +1 self-loop
  }
  if (b == 0 && t == 0) rowptr[N] = E;
  __syncthreads();
  for (int i = beg + t; i < end; i += 256) {
    int2 e = ebuf[i];
    int pos = atomicAdd(&cur[e.y & 255], 1);
    csr[pos] = e.x;
  }
}

// ---- GEMM1 tiled: 64x64 tile/block, BK=32, 16x16 thr x 4x4 micro ----
// h1s[row][d] = dinv[row] * sum_k x[row][k]*W1[k][d]
__global__ __launch_bounds__(256) void k_gemm1(const float* __restrict__ x,
    const float* __restrict__ W1, const float* __restrict__ dinv,
    float* __restrict__ h1s, int N) {
  __shared__ float sX[32][72];  // xT[k][row], stride 72 (16B-aligned rows, 2-way max)
  __shared__ float sW[32][64];  // W[k][d]
  const int t = threadIdx.x;
  const int tx = t & 15, ty = t >> 4;
  const int rowblk = blockIdx.x * 64;
  const int r1 = t >> 3, c4 = t & 7;  // x staging: rows r1, r1+32; k-group c4
  float acc[4][4] = {};
  for (int k0 = 0; k0 < 256; k0 += 32) {
    __syncthreads();
    // stage x (64 rows x 32 k): 2 float4 per thread, transposed into sX
    {
      int ra = rowblk + r1;      if (ra >= N) ra = N - 1;
      int rb = rowblk + r1 + 32; if (rb >= N) rb = N - 1;
      float4 va = *(const float4*)(x + (size_t)ra * 256 + k0 + c4 * 4);
      float4 vb = *(const float4*)(x + (size_t)rb * 256 + k0 + c4 * 4);
      sX[c4 * 4 + 0][r1] = va.x; sX[c4 * 4 + 1][r1] = va.y;
      sX[c4 * 4 + 2][r1] = va.z; sX[c4 * 4 + 3][r1] = va.w;
      sX[c4 * 4 + 0][r1 + 32] = vb.x; sX[c4 * 4 + 1][r1 + 32] = vb.y;
      sX[c4 * 4 + 2][r1 + 32] = vb.z; sX[c4 * 4 + 3][r1 + 32] = vb.w;
    }
    // stage W (32 k x 64 d, contiguous): 2 float4 per thread
    {
      float* sWf = &sW[0][0];
      const float* gw = W1 + (size_t)k0 * 64;
      *(float4*)(sWf + t * 4)        = *(const float4*)(gw + t * 4);
      *(float4*)(sWf + 1024 + t * 4) = *(const float4*)(gw + 1024 + t * 4);
    }
    __syncthreads();
#pragma unroll
    for (int k = 0; k < 32; ++k) {
      float4 xa = *(const float4*)&sX[k][ty * 4];
      float4 wb = *(const float4*)&sW[k][tx * 4];
      acc[0][0] += xa.x * wb.x; acc[0][1] += xa.x * wb.y;
      acc[0][2] += xa.x * wb.z; acc[0][3] += xa.x * wb.w;
      acc[1][0] += xa.y * wb.x; acc[1][1] += xa.y * wb.y;
      acc[1][2] += xa.y * wb.z; acc[1][3] += xa.y * wb.w;
      acc[2][0] += xa.z * wb.x; acc[2][1] += xa.z * wb.y;
      acc[2][2] += xa.z * wb.z; acc[2][3] += xa.z * wb.w;
      acc[3][0] += xa.w * wb.x; acc[3][1] += xa.w * wb.y;
      acc[3][2] += xa.w * wb.z; acc[3][3] += xa.w * wb.w;
    }
  }
#pragma unroll
  for (int i = 0; i < 4; ++i) {
    int row = rowblk + ty * 4 + i;
    if (row < N) {
      float dv = dinv[row];
      float4 o = make_float4(acc[i][0] * dv, acc[i][1] * dv,
                             acc[i][2] * dv, acc[i][3] * dv);
      *(float4*)(h1s + (size_t)row * 64 + tx * 4) = o;
    }
  }
}

// ---- agg1 fused: wave/node, quarter-wave float4 gathers (HID=64) ----
__global__ __launch_bounds__(256) void k_agg1f(const float* __restrict__ h1s,
    const int* __restrict__ rowptr, const int* __restrict__ csr,
    const float* __restrict__ dinv, const float* __restrict__ b1,
    float* __restrict__ hrelu, int N) {
  const int lane = threadIdx.x & 63;
  const int row = blockIdx.x * 4 + (threadIdx.x >> 6);
  if (row >= N) return;
  const int q = lane >> 4, r = lane & 15;
  const int beg = rowptr[row], end = rowptr[row + 1];
  float4 acc = make_float4(0.f, 0.f, 0.f, 0.f);
  for (int b = beg; b < end; b += 64) {
    int m = end - b; if (m > 64) m = 64;
    int idx = (lane < m) ? csr[b + lane] : 0;
    int nIter = (m + 3) >> 2;
    for (int tt = 0; tt < nIter; ++tt) {
      int s = __shfl(idx, 4 * tt + q);
      if (4 * tt + q < m) {
        float4 v = *(const float4*)(h1s + (size_t)s * 64 + r * 4);
        acc.x += v.x; acc.y += v.y; acc.z += v.z; acc.w += v.w;
      }
    }
  }
  // cross-quarter reduce
  acc.x += __shfl_xor(acc.x, 16); acc.y += __shfl_xor(acc.y, 16);
  acc.z += __shfl_xor(acc.z, 16); acc.w += __shfl_xor(acc.w, 16);
  acc.x += __shfl_xor(acc.x, 32); acc.y += __shfl_xor(acc.y, 32);
  acc.z += __shfl_xor(acc.z, 32); acc.w += __shfl_xor(acc.w, 32);
  if (q == 0) {
    float4 self = *(const float4*)(h1s + (size_t)row * 64 + r * 4);
    float4 bb = *(const float4*)(b1 + r * 4);
    float dv = dinv[row];
    float4 o;
    o.x = fmaxf(dv * (acc.x + self.x) + bb.x, 0.f);
    o.y = fmaxf(dv * (acc.y + self.y) + bb.y, 0.f);
    o.z = fmaxf(dv * (acc.z + self.z) + bb.z, 0.f);
    o.w = fmaxf(dv * (acc.w + self.w) + bb.w, 0.f);
    *(float4*)(hrelu + (size_t)row * 64 + r * 4) = o;
  }
}

// ---- GEMM2: h2s[row][d] = dinv[row] * sum_k hrelu[row][k]*W2[k][d]; wave/row ----
__global__ __launch_bounds__(256) void k_gemm2(const float* __restrict__ hrelu,
    const float* __restrict__ W2, const float* __restrict__ dinv,
    float* __restrict__ h2s, int N) {
  const int lane = threadIdx.x & 63;
  const int wid = threadIdx.x >> 6;
  const int l2 = lane < 40 ? lane : 0;
  float w[64];
#pragma unroll
  for (int t = 0; t < 64; ++t) w[t] = W2[t * 40 + l2];
  for (int row = blockIdx.x * 4 + wid; row < N; row += gridDim.x * 4) {
    float xv = hrelu[(size_t)row * 64 + lane];
    float a0 = 0.f, a1 = 0.f, a2 = 0.f, a3 = 0.f;
#pragma unroll
    for (int t = 0; t < 16; ++t) {
      a0 += rl(xv, 4 * t + 0) * w[4 * t + 0];
      a1 += rl(xv, 4 * t + 1) * w[4 * t + 1];
      a2 += rl(xv, 4 * t + 2) * w[4 * t + 2];
      a3 += rl(xv, 4 * t + 3) * w[4 * t + 3];
    }
    if (lane < 40)
      h2s[(size_t)row * 40 + lane] = ((a0 + a1) + (a2 + a3)) * dinv[row];
  }
}

// ---- agg2 fused: wave/node, quarter-wave float4 gathers (OUT=40) ----
__global__ __launch_bounds__(256) void k_agg2f(const float* __restrict__ h2s,
    const int* __restrict__ rowptr, const int* __restrict__ csr,
    const float* __restrict__ dinv, const float* __restrict__ b2,
    float* __restrict__ out, int N) {
  const int lane = threadIdx.x & 63;
  const int row = blockIdx.x * 4 + (threadIdx.x >> 6);
  if (row >= N) return;
  const int q = lane >> 4, r = lane & 15;
  const int beg = rowptr[row], end = rowptr[row + 1];
  float4 acc = make_float4(0.f, 0.f, 0.f, 0.f);
  for (int b = beg; b < end; b += 64) {
    int m = end - b; if (m > 64) m = 64;
    int idx = (lane < m) ? csr[b + lane] : 0;
    int nIter = (m + 3) >> 2;
    for (int tt = 0; tt < nIter; ++tt) {
      int s = __shfl(idx, 4 * tt + q);
      if (r < 10 && 4 * tt + q < m) {
        float4 v = *(const float4*)(h2s + (size_t)s * 40 + r * 4);
        acc.x += v.x; acc.y += v.y; acc.z += v.z; acc.w += v.w;
      }
    }
  }
  acc.x += __shfl_xor(acc.x, 16); acc.y += __shfl_xor(acc.y, 16);
  acc.z += __shfl_xor(acc.z, 16); acc.w += __shfl_xor(acc.w, 16);
  acc.x += __shfl_xor(acc.x, 32); acc.y += __shfl_xor(acc.y, 32);
  acc.z += __shfl_xor(acc.z, 32); acc.w += __shfl_xor(acc.w, 32);
  if (q == 0 && r < 10) {
    float4 self = *(const float4*)(h2s + (size_t)row * 40 + r * 4);
    float4 bb = *(const float4*)(b2 + r * 4);
    float dv = dinv[row];
    float4 o;
    o.x = dv * (acc.x + self.x) + bb.x;
    o.y = dv * (acc.y + self.y) + bb.y;
    o.z = dv * (acc.z + self.z) + bb.z;
    o.w = dv * (acc.w + self.w) + bb.w;
    *(float4*)(out + (size_t)row * 40 + r * 4) = o;
  }
}

extern "C" void kernel_launch(void* const* d_in, const int* in_sizes, int n_in,
                              void* d_out, int out_size, void* d_ws, size_t ws_size,
                              hipStream_t stream) {
  const float* x  = (const float*)d_in[0];
  const int*   ei = (const int*)d_in[1];
  const float* W1 = (const float*)d_in[2];
  const float* b1 = (const float*)d_in[3];
  const float* W2 = (const float*)d_in[4];
  const float* b2 = (const float*)d_in[5];
  float* out = (float*)d_out;

  const int N = in_sizes[0] / 256;
  const int E = in_sizes[1] / 2;
  const int* src = ei;       // edge_index[0]
  const int* dst = ei + E;   // edge_index[1]

  const int nchunk = (E + CHUNK - 1) / CHUNK;   // 391
  const int nbuck  = (N + 255) >> BSH;          // 391 (<=512 assumed)

  // workspace layout (4B units)
  int* ws = (int*)d_ws;
  size_t o = 0;
  int* hist    = ws + o; o += ((size_t)nchunk * nbuck + 1) & ~(size_t)1;
  int* colsum  = ws + o; o += 512;
  int* bstart  = ws + o; o += ((size_t)nbuck + 1 + 1) & ~(size_t)1;
  int* rowptr  = ws + o; o += ((size_t)N + 2) & ~(size_t)1;
  float* dinv  = (float*)(ws + o); o += (size_t)N;
  int* csr     = ws + o; o += (size_t)E;
  float* h1s   = (float*)(ws + o); o += (size_t)N * 64;
  float* hrelu = (float*)(ws + o); o += (size_t)N * 64;
  size_t tail = (o + 1) & ~(size_t)1;
  int2*  ebuf = (int2*)(ws + tail);   // aliases h2s (never live together)
  float* h2s  = (float*)(ws + tail);

  k_hist    <<<nchunk, 256, 0, stream>>>(dst, hist, E, nbuck);
  k_scanA   <<<nbuck, 256, 0, stream>>>(hist, colsum, nchunk, nbuck);
  k_scanB   <<<1, 512, 0, stream>>>(colsum, bstart, nbuck, E);
  k_scatter2<<<nchunk, 256, 0, stream>>>(src, dst, hist, bstart, ebuf, E, nbuck);
  k_csr     <<<nbuck, 256, 0, stream>>>(ebuf, bstart, csr, rowptr, dinv, N, E, nbuck);

  k_gemm1<<<(N + 63) / 64, 256, 0, stream>>>(x, W1, dinv, h1s, N);
  k_agg1f<<<(N + 3) / 4, 256, 0, stream>>>(h1s, rowptr, csr, dinv, b1, hrelu, N);
  k_gemm2<<<2048, 256, 0, stream>>>(hrelu, W2, dinv, h2s, N);
  k_agg2f<<<(N + 3) / 4, 256, 0, stream>>>(h2s, rowptr, csr, dinv, b2, out, N);
}

// Round 5
// 204.052 us; speedup vs baseline: 12.7366x; 1.3320x over previous
//
#include <hip/hip_runtime.h>
#include <hip/hip_fp16.h>

// GCN 2-layer, fp32 math. CSR via bucket sort (no global atomics); tiled GEMM1;
// aggregation = node-per-quarter-wave gather of fp16 messages, fp32 accumulate,
// fp32 self-term/epilogue.

#define CHUNK 4096   // edges per hist/scatter block
#define BSH   8      // bucket = dst >> 8 (256 nodes per bucket)

__device__ __forceinline__ float rl(float v, int l) {
  return __int_as_float(__builtin_amdgcn_readlane(__float_as_int(v), l));
}

// ---- 1. per-chunk bucket histogram (LDS atomics only) ----
__global__ __launch_bounds__(256) void k_hist(const int* __restrict__ dst,
    int* __restrict__ hist, int E, int nbuck) {
  __shared__ int h[512];
  for (int i = threadIdx.x; i < nbuck; i += 256) h[i] = 0;
  __syncthreads();
  int base = blockIdx.x * CHUNK;
  int lim = base + CHUNK < E ? base + CHUNK : E;
  for (int i = base + threadIdx.x; i < lim; i += 256)
    atomicAdd(&h[dst[i] >> BSH], 1);
  __syncthreads();
  for (int i = threadIdx.x; i < nbuck; i += 256)
    hist[(size_t)blockIdx.x * nbuck + i] = h[i];
}

// ---- 2. per-bucket exclusive scan over chunks (in place); column totals ----
__global__ __launch_bounds__(256) void k_scanA(int* __restrict__ hist,
    int* __restrict__ colsum, int nchunk, int nbuck) {
  __shared__ int s[512];
  int b = blockIdx.x, t = threadIdx.x;
  s[t]       = (t < nchunk)       ? hist[(size_t)t * nbuck + b]         : 0;
  s[t + 256] = (t + 256 < nchunk) ? hist[(size_t)(t + 256) * nbuck + b] : 0;
  __syncthreads();
  for (int off = 1; off < 512; off <<= 1) {
    int a0 = (t >= off) ? s[t - off] : 0;
    int a1 = (t + 256 >= off) ? s[t + 256 - off] : 0;
    __syncthreads();
    s[t] += a0; s[t + 256] += a1;
    __syncthreads();
  }
  if (t < nchunk) hist[(size_t)t * nbuck + b] = t ? s[t - 1] : 0;
  if (t + 256 < nchunk) hist[(size_t)(t + 256) * nbuck + b] = s[t + 255];
  if (t == 0) colsum[b] = s[nchunk - 1];
}

// ---- 3. scan bucket totals -> bucket starts ----
__global__ __launch_bounds__(512) void k_scanB(const int* __restrict__ colsum,
    int* __restrict__ bstart, int nbuck, int E) {
  __shared__ int s[512];
  int t = threadIdx.x;
  s[t] = (t < nbuck) ? colsum[t] : 0;
  __syncthreads();
  for (int off = 1; off < 512; off <<= 1) {
    int a = (t >= off) ? s[t - off] : 0;
    __syncthreads();
    s[t] += a;
    __syncthreads();
  }
  if (t < nbuck) bstart[t] = t ? s[t - 1] : 0;
  if (t == 0) bstart[nbuck] = E;
}

// ---- 4. scatter edges into bucket-sorted ebuf (LDS cursors only) ----
__global__ __launch_bounds__(256) void k_scatter2(const int* __restrict__ src,
    const int* __restrict__ dst, const int* __restrict__ hist,
    const int* __restrict__ bstart, int2* __restrict__ ebuf, int E, int nbuck) {
  __shared__ int cur[512];
  for (int i = threadIdx.x; i < nbuck; i += 256)
    cur[i] = bstart[i] + hist[(size_t)blockIdx.x * nbuck + i];
  __syncthreads();
  int base = blockIdx.x * CHUNK;
  int lim = base + CHUNK < E ? base + CHUNK : E;
  for (int i = base + threadIdx.x; i < lim; i += 256) {
    int d = dst[i];
    int pos = atomicAdd(&cur[d >> BSH], 1);
    ebuf[pos] = make_int2(src[i], d);
  }
}

// ---- 5. per-bucket LDS counting sort -> csr, rowptr, dinv ----
__global__ __launch_bounds__(256) void k_csr(const int2* __restrict__ ebuf,
    const int* __restrict__ bstart, int* __restrict__ csr, int* __restrict__ rowptr,
    float* __restrict__ dinv, int N, int E, int nbuck) {
  int b = blockIdx.x, t = threadIdx.x;
  int beg = bstart[b], end = bstart[b + 1];
  __shared__ int s[256];
  __shared__ int cur[256];
  s[t] = 0;
  __syncthreads();
  for (int i = beg + t; i < end; i += 256)
    atomicAdd(&s[ebuf[i].y & 255], 1);
  __syncthreads();
  int cnt = s[t];
  for (int off = 1; off < 256; off <<= 1) {  // inclusive scan
    int a = (t >= off) ? s[t - off] : 0;
    __syncthreads();
    s[t] += a;
    __syncthreads();
  }
  int ex = t ? s[t - 1] : 0;
  cur[t] = beg + ex;
  int node = (b << BSH) + t;
  if (node < N) {
    rowptr[node] = beg + ex;
    dinv[node] = rsqrtf((float)cnt + 1.0f);  // +1 self-loop
  }
  if (b == 0 && t == 0) rowptr[N] = E;
  __syncthreads();
  for (int i = beg + t; i < end; i += 256) {
    int2 e = ebuf[i];
    int pos = atomicAdd(&cur[e.y & 255], 1);
    csr[pos] = e.x;
  }
}

// ---- GEMM1 tiled: 64x64 tile/block, BK=32, 16x16 thr x 4x4 micro ----
// h1s = (x@W1)*dinv[row]  (fp32) ; h1h = fp16 copy for gathers
__global__ __launch_bounds__(256) void k_gemm1(const float* __restrict__ x,
    const float* __restrict__ W1, const float* __restrict__ dinv,
    float* __restrict__ h1s, __half* __restrict__ h1h, int N) {
  __shared__ float sX[32][72];  // xT[k][row]
  __shared__ float sW[32][64];  // W[k][d]
  const int t = threadIdx.x;
  const int tx = t & 15, ty = t >> 4;
  const int rowblk = blockIdx.x * 64;
  const int r1 = t >> 3, c4 = t & 7;
  float acc[4][4] = {};
  for (int k0 = 0; k0 < 256; k0 += 32) {
    __syncthreads();
    {
      int ra = rowblk + r1;      if (ra >= N) ra = N - 1;
      int rb = rowblk + r1 + 32; if (rb >= N) rb = N - 1;
      float4 va = *(const float4*)(x + (size_t)ra * 256 + k0 + c4 * 4);
      float4 vb = *(const float4*)(x + (size_t)rb * 256 + k0 + c4 * 4);
      sX[c4 * 4 + 0][r1] = va.x; sX[c4 * 4 + 1][r1] = va.y;
      sX[c4 * 4 + 2][r1] = va.z; sX[c4 * 4 + 3][r1] = va.w;
      sX[c4 * 4 + 0][r1 + 32] = vb.x; sX[c4 * 4 + 1][r1 + 32] = vb.y;
      sX[c4 * 4 + 2][r1 + 32] = vb.z; sX[c4 * 4 + 3][r1 + 32] = vb.w;
    }
    {
      float* sWf = &sW[0][0];
      const float* gw = W1 + (size_t)k0 * 64;
      *(float4*)(sWf + t * 4)        = *(const float4*)(gw + t * 4);
      *(float4*)(sWf + 1024 + t * 4) = *(const float4*)(gw + 1024 + t * 4);
    }
    __syncthreads();
#pragma unroll
    for (int k = 0; k < 32; ++k) {
      float4 xa = *(const float4*)&sX[k][ty * 4];
      float4 wb = *(const float4*)&sW[k][tx * 4];
      acc[0][0] += xa.x * wb.x; acc[0][1] += xa.x * wb.y;
      acc[0][2] += xa.x * wb.z; acc[0][3] += xa.x * wb.w;
      acc[1][0] += xa.y * wb.x; acc[1][1] += xa.y * wb.y;
      acc[1][2] += xa.y * wb.z; acc[1][3] += xa.y * wb.w;
      acc[2][0] += xa.z * wb.x; acc[2][1] += xa.z * wb.y;
      acc[2][2] += xa.z * wb.z; acc[2][3] += xa.z * wb.w;
      acc[3][0] += xa.w * wb.x; acc[3][1] += xa.w * wb.y;
      acc[3][2] += xa.w * wb.z; acc[3][3] += xa.w * wb.w;
    }
  }
#pragma unroll
  for (int i = 0; i < 4; ++i) {
    int row = rowblk + ty * 4 + i;
    if (row < N) {
      float dv = dinv[row];
      float4 o = make_float4(acc[i][0] * dv, acc[i][1] * dv,
                             acc[i][2] * dv, acc[i][3] * dv);
      *(float4*)(h1s + (size_t)row * 64 + tx * 4) = o;
      __half2* hp = (__half2*)(h1h + (size_t)row * 64 + tx * 4);
      hp[0] = __floats2half2_rn(o.x, o.y);
      hp[1] = __floats2half2_rn(o.z, o.w);
    }
  }
}

#define HADD(S, HPTR, W) { \
    uint2 u_ = *(const uint2*)((HPTR) + ((size_t)(S) * (W) + r * 4)); \
    union { unsigned v; __half2 h; } c0_, c1_; c0_.v = u_.x; c1_.v = u_.y; \
    float2 f0_ = __half22float2(c0_.h), f1_ = __half22float2(c1_.h); \
    acc.x += f0_.x; acc.y += f0_.y; acc.z += f1_.x; acc.w += f1_.y; }

// ---- agg1: node per quarter-wave; fp16 gathers, fp32 self/epilogue (HID=64) ----
__global__ __launch_bounds__(256) void k_agg1f(const float* __restrict__ h1s,
    const __half* __restrict__ h1h, const int* __restrict__ rowptr,
    const int* __restrict__ csr, const float* __restrict__ dinv,
    const float* __restrict__ b1, float* __restrict__ hrelu, int N) {
  const int t = threadIdx.x;
  const int r = t & 15;
  const int qq = (t >> 4) & 3;             // quarter within wave
  const int row = blockIdx.x * 16 + (t >> 4);
  if (row >= N) return;
  const int beg = rowptr[row], end = rowptr[row + 1];
  float4 acc = make_float4(0.f, 0.f, 0.f, 0.f);
  for (int b = beg; b < end; b += 16) {
    int m = end - b; if (m > 16) m = 16;
    int idx = (r < m) ? csr[b + r] : 0;
    int tt = 0;
    for (; tt + 4 <= m; tt += 4) {
      int s0 = __shfl(idx, qq * 16 + tt + 0);
      int s1 = __shfl(idx, qq * 16 + tt + 1);
      int s2 = __shfl(idx, qq * 16 + tt + 2);
      int s3 = __shfl(idx, qq * 16 + tt + 3);
      HADD(s0, h1h, 64); HADD(s1, h1h, 64);
      HADD(s2, h1h, 64); HADD(s3, h1h, 64);
    }
    for (; tt < m; ++tt) {
      int s0 = __shfl(idx, qq * 16 + tt);
      HADD(s0, h1h, 64);
    }
  }
  float4 self = *(const float4*)(h1s + (size_t)row * 64 + r * 4);
  float4 bb = *(const float4*)(b1 + r * 4);
  float dv = dinv[row];
  float4 o;
  o.x = fmaxf(dv * (acc.x + self.x) + bb.x, 0.f);
  o.y = fmaxf(dv * (acc.y + self.y) + bb.y, 0.f);
  o.z = fmaxf(dv * (acc.z + self.z) + bb.z, 0.f);
  o.w = fmaxf(dv * (acc.w + self.w) + bb.w, 0.f);
  *(float4*)(hrelu + (size_t)row * 64 + r * 4) = o;
}

// ---- GEMM2: h2s = (hrelu@W2)*dinv[row] (fp32) ; h2h = fp16 copy ----
__global__ __launch_bounds__(256) void k_gemm2(const float* __restrict__ hrelu,
    const float* __restrict__ W2, const float* __restrict__ dinv,
    float* __restrict__ h2s, __half* __restrict__ h2h, int N) {
  const int lane = threadIdx.x & 63;
  const int wid = threadIdx.x >> 6;
  const int l2 = lane < 40 ? lane : 0;
  float w[64];
#pragma unroll
  for (int t = 0; t < 64; ++t) w[t] = W2[t * 40 + l2];
  for (int row = blockIdx.x * 4 + wid; row < N; row += gridDim.x * 4) {
    float xv = hrelu[(size_t)row * 64 + lane];
    float a0 = 0.f, a1 = 0.f, a2 = 0.f, a3 = 0.f;
#pragma unroll
    for (int t = 0; t < 16; ++t) {
      a0 += rl(xv, 4 * t + 0) * w[4 * t + 0];
      a1 += rl(xv, 4 * t + 1) * w[4 * t + 1];
      a2 += rl(xv, 4 * t + 2) * w[4 * t + 2];
      a3 += rl(xv, 4 * t + 3) * w[4 * t + 3];
    }
    if (lane < 40) {
      float v = ((a0 + a1) + (a2 + a3)) * dinv[row];
      h2s[(size_t)row * 40 + lane] = v;
      h2h[(size_t)row * 40 + lane] = __float2half(v);
    }
  }
}

// ---- agg2: node per quarter-wave; fp16 gathers (OUT=40) ----
__global__ __launch_bounds__(256) void k_agg2f(const float* __restrict__ h2s,
    const __half* __restrict__ h2h, const int* __restrict__ rowptr,
    const int* __restrict__ csr, const float* __restrict__ dinv,
    const float* __restrict__ b2, float* __restrict__ out, int N) {
  const int t = threadIdx.x;
  const int r = t & 15;
  const int qq = (t >> 4) & 3;
  const int row = blockIdx.x * 16 + (t >> 4);
  if (row >= N) return;
  const int beg = rowptr[row], end = rowptr[row + 1];
  float4 acc = make_float4(0.f, 0.f, 0.f, 0.f);
  const bool act = (r < 10);
  for (int b = beg; b < end; b += 16) {
    int m = end - b; if (m > 16) m = 16;
    int idx = (r < m) ? csr[b + r] : 0;
    int tt = 0;
    for (; tt + 4 <= m; tt += 4) {
      int s0 = __shfl(idx, qq * 16 + tt + 0);
      int s1 = __shfl(idx, qq * 16 + tt + 1);
      int s2 = __shfl(idx, qq * 16 + tt + 2);
      int s3 = __shfl(idx, qq * 16 + tt + 3);
      if (act) { HADD(s0, h2h, 40); HADD(s1, h2h, 40);
                 HADD(s2, h2h, 40); HADD(s3, h2h, 40); }
    }
    for (; tt < m; ++tt) {
      int s0 = __shfl(idx, qq * 16 + tt);
      if (act) HADD(s0, h2h, 40);
    }
  }
  if (act) {
    float4 self = *(const float4*)(h2s + (size_t)row * 40 + r * 4);
    float4 bb = *(const float4*)(b2 + r * 4);
    float dv = dinv[row];
    float4 o;
    o.x = dv * (acc.x + self.x) + bb.x;
    o.y = dv * (acc.y + self.y) + bb.y;
    o.z = dv * (acc.z + self.z) + bb.z;
    o.w = dv * (acc.w + self.w) + bb.w;
    *(float4*)(out + (size_t)row * 40 + r * 4) = o;
  }
}

extern "C" void kernel_launch(void* const* d_in, const int* in_sizes, int n_in,
                              void* d_out, int out_size, void* d_ws, size_t ws_size,
                              hipStream_t stream) {
  const float* x  = (const float*)d_in[0];
  const int*   ei = (const int*)d_in[1];
  const float* W1 = (const float*)d_in[2];
  const float* b1 = (const float*)d_in[3];
  const float* W2 = (const float*)d_in[4];
  const float* b2 = (const float*)d_in[5];
  float* out = (float*)d_out;

  const int N = in_sizes[0] / 256;
  const int E = in_sizes[1] / 2;
  const int* src = ei;       // edge_index[0]
  const int* dst = ei + E;   // edge_index[1]

  const int nchunk = (E + CHUNK - 1) / CHUNK;
  const int nbuck  = (N + 255) >> BSH;

  // workspace layout (4B units; regions 16B-aligned)
  int* ws = (int*)d_ws;
  size_t o = 0;
  auto align4 = [](size_t v) { return (v + 3) & ~(size_t)3; };
  int* hist    = ws + o; o = align4(o + (size_t)nchunk * nbuck);
  int* colsum  = ws + o; o = align4(o + 512);
  int* bstart  = ws + o; o = align4(o + nbuck + 1);
  int* rowptr  = ws + o; o = align4(o + (size_t)N + 1);
  float* dinv  = (float*)(ws + o); o = align4(o + (size_t)N);
  int* csr     = ws + o; o = align4(o + (size_t)E);
  // region A: ebuf (E int2) then reused as h1h (N*64 half = N*32 int)
  size_t szA = (size_t)E * 2; { size_t a2 = (size_t)N * 32; if (a2 > szA) szA = a2; }
  int2*   ebuf = (int2*)(ws + o);
  __half* h1h  = (__half*)(ws + o); o = align4(o + szA);
  // region B: h1s (N*64 f32) then reused as h2s (N*40 f32) + h2h (N*40 half)
  float*  h1s = (float*)(ws + o);
  float*  h2s = (float*)(ws + o);
  __half* h2h = (__half*)(ws + o + (size_t)N * 40); o = align4(o + (size_t)N * 64);
  float* hrelu = (float*)(ws + o); o += (size_t)N * 64;

  k_hist    <<<nchunk, 256, 0, stream>>>(dst, hist, E, nbuck);
  k_scanA   <<<nbuck, 256, 0, stream>>>(hist, colsum, nchunk, nbuck);
  k_scanB   <<<1, 512, 0, stream>>>(colsum, bstart, nbuck, E);
  k_scatter2<<<nchunk, 256, 0, stream>>>(src, dst, hist, bstart, ebuf, E, nbuck);
  k_csr     <<<nbuck, 256, 0, stream>>>(ebuf, bstart, csr, rowptr, dinv, N, E, nbuck);

  k_gemm1<<<(N + 63) / 64, 256, 0, stream>>>(x, W1, dinv, h1s, h1h, N);
  k_agg1f<<<(N + 15) / 16, 256, 0, stream>>>(h1s, h1h, rowptr, csr, dinv, b1, hrelu, N);
  k_gemm2<<<2048, 256, 0, stream>>>(hrelu, W2, dinv, h2s, h2h, N);
  k_agg2f<<<(N + 15) / 16, 256, 0, stream>>>(h2s, h2h, rowptr, csr, dinv, b2, out, N);
}

// Round 6
// 196.569 us; speedup vs baseline: 13.2214x; 1.0381x over previous
//
#include <hip/hip_runtime.h>
#include <hip/hip_fp16.h>

// GCN 2-layer, fp32 math + fp16 MFMA for GEMM1 + fp16 message gathers.
// CSR via bucket sort (no global atomics).

#define CHUNK 4096   // edges per hist/scatter block
#define BSH   8      // bucket = dst >> 8 (256 nodes per bucket)

typedef _Float16 half8 __attribute__((ext_vector_type(8)));
typedef float f32x4 __attribute__((ext_vector_type(4)));

__device__ __forceinline__ float rl(float v, int l) {
  return __int_as_float(__builtin_amdgcn_readlane(__float_as_int(v), l));
}

// ---- 1. per-chunk bucket histogram (LDS atomics only) ----
__global__ __launch_bounds__(256) void k_hist(const int* __restrict__ dst,
    int* __restrict__ hist, int E, int nbuck) {
  __shared__ int h[512];
  for (int i = threadIdx.x; i < nbuck; i += 256) h[i] = 0;
  __syncthreads();
  int base = blockIdx.x * CHUNK;
  int lim = base + CHUNK < E ? base + CHUNK : E;
  for (int i = base + threadIdx.x; i < lim; i += 256)
    atomicAdd(&h[dst[i] >> BSH], 1);
  __syncthreads();
  for (int i = threadIdx.x; i < nbuck; i += 256)
    hist[(size_t)blockIdx.x * nbuck + i] = h[i];
}

// ---- 2. per-bucket exclusive scan over chunks (in place); column totals ----
__global__ __launch_bounds__(256) void k_scanA(int* __restrict__ hist,
    int* __restrict__ colsum, int nchunk, int nbuck) {
  __shared__ int s[512];
  int b = blockIdx.x, t = threadIdx.x;
  s[t]       = (t < nchunk)       ? hist[(size_t)t * nbuck + b]         : 0;
  s[t + 256] = (t + 256 < nchunk) ? hist[(size_t)(t + 256) * nbuck + b] : 0;
  __syncthreads();
  for (int off = 1; off < 512; off <<= 1) {
    int a0 = (t >= off) ? s[t - off] : 0;
    int a1 = (t + 256 >= off) ? s[t + 256 - off] : 0;
    __syncthreads();
    s[t] += a0; s[t + 256] += a1;
    __syncthreads();
  }
  if (t < nchunk) hist[(size_t)t * nbuck + b] = t ? s[t - 1] : 0;
  if (t + 256 < nchunk) hist[(size_t)(t + 256) * nbuck + b] = s[t + 255];
  if (t == 0) colsum[b] = s[nchunk - 1];
}

// ---- 3. scan bucket totals -> bucket starts ----
__global__ __launch_bounds__(512) void k_scanB(const int* __restrict__ colsum,
    int* __restrict__ bstart, int nbuck, int E) {
  __shared__ int s[512];
  int t = threadIdx.x;
  s[t] = (t < nbuck) ? colsum[t] : 0;
  __syncthreads();
  for (int off = 1; off < 512; off <<= 1) {
    int a = (t >= off) ? s[t - off] : 0;
    __syncthreads();
    s[t] += a;
    __syncthreads();
  }
  if (t < nbuck) bstart[t] = t ? s[t - 1] : 0;
  if (t == 0) bstart[nbuck] = E;
}

// ---- 4. scatter edges into bucket-sorted ebuf (LDS cursors only) ----
__global__ __launch_bounds__(256) void k_scatter2(const int* __restrict__ src,
    const int* __restrict__ dst, const int* __restrict__ hist,
    const int* __restrict__ bstart, int2* __restrict__ ebuf, int E, int nbuck) {
  __shared__ int cur[512];
  for (int i = threadIdx.x; i < nbuck; i += 256)
    cur[i] = bstart[i] + hist[(size_t)blockIdx.x * nbuck + i];
  __syncthreads();
  int base = blockIdx.x * CHUNK;
  int lim = base + CHUNK < E ? base + CHUNK : E;
  for (int i = base + threadIdx.x; i < lim; i += 256) {
    int d = dst[i];
    int pos = atomicAdd(&cur[d >> BSH], 1);
    ebuf[pos] = make_int2(src[i], d);
  }
}

// ---- 5. per-bucket LDS counting sort -> csr, rowptr, dinv ----
__global__ __launch_bounds__(256) void k_csr(const int2* __restrict__ ebuf,
    const int* __restrict__ bstart, int* __restrict__ csr, int* __restrict__ rowptr,
    float* __restrict__ dinv, int N, int E, int nbuck) {
  int b = blockIdx.x, t = threadIdx.x;
  int beg = bstart[b], end = bstart[b + 1];
  __shared__ int s[256];
  __shared__ int cur[256];
  s[t] = 0;
  __syncthreads();
  for (int i = beg + t; i < end; i += 256)
    atomicAdd(&s[ebuf[i].y & 255], 1);
  __syncthreads();
  int cnt = s[t];
  for (int off = 1; off < 256; off <<= 1) {  // inclusive scan
    int a = (t >= off) ? s[t - off] : 0;
    __syncthreads();
    s[t] += a;
    __syncthreads();
  }
  int ex = t ? s[t - 1] : 0;
  cur[t] = beg + ex;
  int node = (b << BSH) + t;
  if (node < N) {
    rowptr[node] = beg + ex;
    dinv[node] = rsqrtf((float)cnt + 1.0f);  // +1 self-loop
  }
  if (b == 0 && t == 0) rowptr[N] = E;
  __syncthreads();
  for (int i = beg + t; i < end; i += 256) {
    int2 e = ebuf[i];
    int pos = atomicAdd(&cur[e.y & 255], 1);
    csr[pos] = e.x;
  }
}

// ---- 0b. W1 [256][64] fp32 -> W1hT [64][256] fp16 (once, 1 block) ----
__global__ __launch_bounds__(256) void k_wcast(const float* __restrict__ W1,
    _Float16* __restrict__ whT) {
  const int t = threadIdx.x;
  const int d = t & 63;
  const int kb = (t >> 6) * 64;          // 64 k per thread
  for (int i = 0; i < 8; ++i) {
    int k = kb + i * 8;
    half8 v;
#pragma unroll
    for (int j = 0; j < 8; ++j) v[j] = (_Float16)W1[(size_t)(k + j) * 64 + d];
    *(half8*)(whT + (size_t)d * 256 + k) = v;
  }
}

// ---- GEMM1 via MFMA f16: wave computes 16 rows x 64 cols, K=256; NO LDS ----
// h1s = (x@W1)*dinv[row] fp32 ; h1h = fp16 copy
__global__ __launch_bounds__(256) void k_gemm1(const float* __restrict__ x,
    const _Float16* __restrict__ whT, const float* __restrict__ dinv,
    float* __restrict__ h1s, __half* __restrict__ h1h, int N) {
  const int l = threadIdx.x & 63;
  const int wid = threadIdx.x >> 6;
  const int r0 = (blockIdx.x * 4 + wid) * 16;
  if (r0 >= N) return;
  const int c0 = l & 15;          // col within tile / row within wave-tile (A)
  const int q = l >> 4;           // k-octet selector
  const int arow = r0 + c0;       // this lane's A row
  f32x4 acc0 = {0.f, 0.f, 0.f, 0.f}, acc1 = {0.f, 0.f, 0.f, 0.f};
  f32x4 acc2 = {0.f, 0.f, 0.f, 0.f}, acc3 = {0.f, 0.f, 0.f, 0.f};
#pragma unroll
  for (int step = 0; step < 8; ++step) {
    const int kb = step * 32 + q * 8;
    float4 xa = *(const float4*)(x + (size_t)arow * 256 + kb);
    float4 xb = *(const float4*)(x + (size_t)arow * 256 + kb + 4);
    half8 aF;
    aF[0] = (_Float16)xa.x; aF[1] = (_Float16)xa.y;
    aF[2] = (_Float16)xa.z; aF[3] = (_Float16)xa.w;
    aF[4] = (_Float16)xb.x; aF[5] = (_Float16)xb.y;
    aF[6] = (_Float16)xb.z; aF[7] = (_Float16)xb.w;
    half8 b0 = *(const half8*)(whT + (size_t)(c0)      * 256 + kb);
    half8 b1 = *(const half8*)(whT + (size_t)(c0 + 16) * 256 + kb);
    half8 b2 = *(const half8*)(whT + (size_t)(c0 + 32) * 256 + kb);
    half8 b3 = *(const half8*)(whT + (size_t)(c0 + 48) * 256 + kb);
    acc0 = __builtin_amdgcn_mfma_f32_16x16x32_f16(aF, b0, acc0, 0, 0, 0);
    acc1 = __builtin_amdgcn_mfma_f32_16x16x32_f16(aF, b1, acc1, 0, 0, 0);
    acc2 = __builtin_amdgcn_mfma_f32_16x16x32_f16(aF, b2, acc2, 0, 0, 0);
    acc3 = __builtin_amdgcn_mfma_f32_16x16x32_f16(aF, b3, acc3, 0, 0, 0);
  }
  // C/D: col = lane&15 (+16n), row = (lane>>4)*4 + j
#pragma unroll
  for (int j = 0; j < 4; ++j) {
    int row = r0 + q * 4 + j;
    float dv = dinv[row];
    float v0 = acc0[j] * dv, v1 = acc1[j] * dv, v2 = acc2[j] * dv, v3 = acc3[j] * dv;
    float* po = h1s + (size_t)row * 64 + c0;
    po[0] = v0; po[16] = v1; po[32] = v2; po[48] = v3;
    __half* ph = h1h + (size_t)row * 64 + c0;
    ph[0] = __float2half(v0); ph[16] = __float2half(v1);
    ph[32] = __float2half(v2); ph[48] = __float2half(v3);
  }
}

#define HADD(S, HPTR, W) { \
    uint2 u_ = *(const uint2*)((HPTR) + ((size_t)(S) * (W) + r * 4)); \
    union { unsigned v; __half2 h; } c0_, c1_; c0_.v = u_.x; c1_.v = u_.y; \
    float2 f0_ = __half22float2(c0_.h), f1_ = __half22float2(c1_.h); \
    acc.x += f0_.x; acc.y += f0_.y; acc.z += f1_.x; acc.w += f1_.y; }

// ---- agg1: node per quarter-wave; fp16 gathers, fp32 self/epilogue (HID=64) ----
__global__ __launch_bounds__(256) void k_agg1f(const float* __restrict__ h1s,
    const __half* __restrict__ h1h, const int* __restrict__ rowptr,
    const int* __restrict__ csr, const float* __restrict__ dinv,
    const float* __restrict__ b1, float* __restrict__ hrelu, int N) {
  const int t = threadIdx.x;
  const int r = t & 15;
  const int qq = (t >> 4) & 3;             // quarter within wave
  const int row = blockIdx.x * 16 + (t >> 4);
  if (row >= N) return;
  const int beg = rowptr[row], end = rowptr[row + 1];
  float4 acc = make_float4(0.f, 0.f, 0.f, 0.f);
  for (int b = beg; b < end; b += 16) {
    int m = end - b; if (m > 16) m = 16;
    int idx = (r < m) ? csr[b + r] : 0;
    int tt = 0;
    for (; tt + 4 <= m; tt += 4) {
      int s0 = __shfl(idx, qq * 16 + tt + 0);
      int s1 = __shfl(idx, qq * 16 + tt + 1);
      int s2 = __shfl(idx, qq * 16 + tt + 2);
      int s3 = __shfl(idx, qq * 16 + tt + 3);
      HADD(s0, h1h, 64); HADD(s1, h1h, 64);
      HADD(s2, h1h, 64); HADD(s3, h1h, 64);
    }
    for (; tt < m; ++tt) {
      int s0 = __shfl(idx, qq * 16 + tt);
      HADD(s0, h1h, 64);
    }
  }
  float4 self = *(const float4*)(h1s + (size_t)row * 64 + r * 4);
  float4 bb = *(const float4*)(b1 + r * 4);
  float dv = dinv[row];
  float4 o;
  o.x = fmaxf(dv * (acc.x + self.x) + bb.x, 0.f);
  o.y = fmaxf(dv * (acc.y + self.y) + bb.y, 0.f);
  o.z = fmaxf(dv * (acc.z + self.z) + bb.z, 0.f);
  o.w = fmaxf(dv * (acc.w + self.w) + bb.w, 0.f);
  *(float4*)(hrelu + (size_t)row * 64 + r * 4) = o;
}

// ---- GEMM2: h2s = (hrelu@W2)*dinv[row] (fp32) ; h2h = fp16 copy ----
__global__ __launch_bounds__(256) void k_gemm2(const float* __restrict__ hrelu,
    const float* __restrict__ W2, const float* __restrict__ dinv,
    float* __restrict__ h2s, __half* __restrict__ h2h, int N) {
  const int lane = threadIdx.x & 63;
  const int wid = threadIdx.x >> 6;
  const int l2 = lane < 40 ? lane : 0;
  float w[64];
#pragma unroll
  for (int t = 0; t < 64; ++t) w[t] = W2[t * 40 + l2];
  for (int row = blockIdx.x * 4 + wid; row < N; row += gridDim.x * 4) {
    float xv = hrelu[(size_t)row * 64 + lane];
    float a0 = 0.f, a1 = 0.f, a2 = 0.f, a3 = 0.f;
#pragma unroll
    for (int t = 0; t < 16; ++t) {
      a0 += rl(xv, 4 * t + 0) * w[4 * t + 0];
      a1 += rl(xv, 4 * t + 1) * w[4 * t + 1];
      a2 += rl(xv, 4 * t + 2) * w[4 * t + 2];
      a3 += rl(xv, 4 * t + 3) * w[4 * t + 3];
    }
    if (lane < 40) {
      float v = ((a0 + a1) + (a2 + a3)) * dinv[row];
      h2s[(size_t)row * 40 + lane] = v;
      h2h[(size_t)row * 40 + lane] = __float2half(v);
    }
  }
}

// ---- agg2: node per quarter-wave; fp16 gathers (OUT=40) ----
__global__ __launch_bounds__(256) void k_agg2f(const float* __restrict__ h2s,
    const __half* __restrict__ h2h, const int* __restrict__ rowptr,
    const int* __restrict__ csr, const float* __restrict__ dinv,
    const float* __restrict__ b2, float* __restrict__ out, int N) {
  const int t = threadIdx.x;
  const int r = t & 15;
  const int qq = (t >> 4) & 3;
  const int row = blockIdx.x * 16 + (t >> 4);
  if (row >= N) return;
  const int beg = rowptr[row], end = rowptr[row + 1];
  float4 acc = make_float4(0.f, 0.f, 0.f, 0.f);
  const bool act = (r < 10);
  for (int b = beg; b < end; b += 16) {
    int m = end - b; if (m > 16) m = 16;
    int idx = (r < m) ? csr[b + r] : 0;
    int tt = 0;
    for (; tt + 4 <= m; tt += 4) {
      int s0 = __shfl(idx, qq * 16 + tt + 0);
      int s1 = __shfl(idx, qq * 16 + tt + 1);
      int s2 = __shfl(idx, qq * 16 + tt + 2);
      int s3 = __shfl(idx, qq * 16 + tt + 3);
      if (act) { HADD(s0, h2h, 40); HADD(s1, h2h, 40);
                 HADD(s2, h2h, 40); HADD(s3, h2h, 40); }
    }
    for (; tt < m; ++tt) {
      int s0 = __shfl(idx, qq * 16 + tt);
      if (act) HADD(s0, h2h, 40);
    }
  }
  if (act) {
    float4 self = *(const float4*)(h2s + (size_t)row * 40 + r * 4);
    float4 bb = *(const float4*)(b2 + r * 4);
    float dv = dinv[row];
    float4 o;
    o.x = dv * (acc.x + self.x) + bb.x;
    o.y = dv * (acc.y + self.y) + bb.y;
    o.z = dv * (acc.z + self.z) + bb.z;
    o.w = dv * (acc.w + self.w) + bb.w;
    *(float4*)(out + (size_t)row * 40 + r * 4) = o;
  }
}

extern "C" void kernel_launch(void* const* d_in, const int* in_sizes, int n_in,
                              void* d_out, int out_size, void* d_ws, size_t ws_size,
                              hipStream_t stream) {
  const float* x  = (const float*)d_in[0];
  const int*   ei = (const int*)d_in[1];
  const float* W1 = (const float*)d_in[2];
  const float* b1 = (const float*)d_in[3];
  const float* W2 = (const float*)d_in[4];
  const float* b2 = (const float*)d_in[5];
  float* out = (float*)d_out;

  const int N = in_sizes[0] / 256;
  const int E = in_sizes[1] / 2;
  const int* src = ei;       // edge_index[0]
  const int* dst = ei + E;   // edge_index[1]

  const int nchunk = (E + CHUNK - 1) / CHUNK;
  const int nbuck  = (N + 255) >> BSH;

  // workspace layout (4B units; regions 16B-aligned)
  int* ws = (int*)d_ws;
  size_t o = 0;
  auto align4 = [](size_t v) { return (v + 3) & ~(size_t)3; };
  int* hist    = ws + o; o = align4(o + (size_t)nchunk * nbuck);
  int* colsum  = ws + o; o = align4(o + 512);
  int* bstart  = ws + o; o = align4(o + nbuck + 1);
  int* rowptr  = ws + o; o = align4(o + (size_t)N + 1);
  float* dinv  = (float*)(ws + o); o = align4(o + (size_t)N);
  int* csr     = ws + o; o = align4(o + (size_t)E);
  _Float16* whT = (_Float16*)(ws + o); o = align4(o + 64 * 256 / 2);  // 32 KB
  // region A: ebuf (E int2) then reused as h1h (N*64 half = N*32 int)
  size_t szA = (size_t)E * 2; { size_t a2 = (size_t)N * 32; if (a2 > szA) szA = a2; }
  int2*   ebuf = (int2*)(ws + o);
  __half* h1h  = (__half*)(ws + o); o = align4(o + szA);
  // region B: h1s (N*64 f32) then reused as h2s (N*40 f32) + h2h (N*40 half)
  float*  h1s = (float*)(ws + o);
  float*  h2s = (float*)(ws + o);
  __half* h2h = (__half*)(ws + o + (size_t)N * 40); o = align4(o + (size_t)N * 64);
  float* hrelu = (float*)(ws + o); o += (size_t)N * 64;

  k_hist    <<<nchunk, 256, 0, stream>>>(dst, hist, E, nbuck);
  k_scanA   <<<nbuck, 256, 0, stream>>>(hist, colsum, nchunk, nbuck);
  k_scanB   <<<1, 512, 0, stream>>>(colsum, bstart, nbuck, E);
  k_wcast   <<<1, 256, 0, stream>>>(W1, whT);
  k_scatter2<<<nchunk, 256, 0, stream>>>(src, dst, hist, bstart, ebuf, E, nbuck);
  k_csr     <<<nbuck, 256, 0, stream>>>(ebuf, bstart, csr, rowptr, dinv, N, E, nbuck);

  int nwave = (N + 15) / 16;
  k_gemm1<<<(nwave + 3) / 4, 256, 0, stream>>>(x, whT, dinv, h1s, h1h, N);
  k_agg1f<<<(N + 15) / 16, 256, 0, stream>>>(h1s, h1h, rowptr, csr, dinv, b1, hrelu, N);
  k_gemm2<<<2048, 256, 0, stream>>>(hrelu, W2, dinv, h2s, h2h, N);
  k_agg2f<<<(N + 15) / 16, 256, 0, stream>>>(h2s, h2h, rowptr, csr, dinv, b2, out, N);
}

// Round 7
// 189.003 us; speedup vs baseline: 13.7507x; 1.0400x over previous
//
#include <hip/hip_runtime.h>
#include <hip/hip_fp16.h>

// GCN 2-layer. fp16 MFMA GEMM1 (loads hoisted), fp16 messages everywhere,
// fp32 accumulation. CSR via bucket sort (no global atomics).

#define CHUNK 4096   // edges per hist/scatter block
#define BSH   8      // bucket = dst >> 8 (256 nodes per bucket)

typedef _Float16 half8 __attribute__((ext_vector_type(8)));
typedef float f32x4 __attribute__((ext_vector_type(4)));

__device__ __forceinline__ float rl(float v, int l) {
  return __int_as_float(__builtin_amdgcn_readlane(__float_as_int(v), l));
}

// ---- 1. per-chunk bucket histogram (LDS atomics only) ----
__global__ __launch_bounds__(256) void k_hist(const int* __restrict__ dst,
    int* __restrict__ hist, int E, int nbuck) {
  __shared__ int h[512];
  for (int i = threadIdx.x; i < nbuck; i += 256) h[i] = 0;
  __syncthreads();
  int base = blockIdx.x * CHUNK;
  int lim = base + CHUNK < E ? base + CHUNK : E;
  for (int i = base + threadIdx.x; i < lim; i += 256)
    atomicAdd(&h[dst[i] >> BSH], 1);
  __syncthreads();
  for (int i = threadIdx.x; i < nbuck; i += 256)
    hist[(size_t)blockIdx.x * nbuck + i] = h[i];
}

// ---- 2. per-bucket exclusive scan over chunks (in place); column totals ----
__global__ __launch_bounds__(256) void k_scanA(int* __restrict__ hist,
    int* __restrict__ colsum, int nchunk, int nbuck) {
  __shared__ int s[512];
  int b = blockIdx.x, t = threadIdx.x;
  s[t]       = (t < nchunk)       ? hist[(size_t)t * nbuck + b]         : 0;
  s[t + 256] = (t + 256 < nchunk) ? hist[(size_t)(t + 256) * nbuck + b] : 0;
  __syncthreads();
  for (int off = 1; off < 512; off <<= 1) {
    int a0 = (t >= off) ? s[t - off] : 0;
    int a1 = (t + 256 >= off) ? s[t + 256 - off] : 0;
    __syncthreads();
    s[t] += a0; s[t + 256] += a1;
    __syncthreads();
  }
  if (t < nchunk) hist[(size_t)t * nbuck + b] = t ? s[t - 1] : 0;
  if (t + 256 < nchunk) hist[(size_t)(t + 256) * nbuck + b] = s[t + 255];
  if (t == 0) colsum[b] = s[nchunk - 1];
}

// ---- 3. scan bucket totals -> bucket starts ----
__global__ __launch_bounds__(512) void k_scanB(const int* __restrict__ colsum,
    int* __restrict__ bstart, int nbuck, int E) {
  __shared__ int s[512];
  int t = threadIdx.x;
  s[t] = (t < nbuck) ? colsum[t] : 0;
  __syncthreads();
  for (int off = 1; off < 512; off <<= 1) {
    int a = (t >= off) ? s[t - off] : 0;
    __syncthreads();
    s[t] += a;
    __syncthreads();
  }
  if (t < nbuck) bstart[t] = t ? s[t - 1] : 0;
  if (t == 0) bstart[nbuck] = E;
}

// ---- 4. scatter edges into bucket-sorted ebuf (LDS cursors only) ----
__global__ __launch_bounds__(256) void k_scatter2(const int* __restrict__ src,
    const int* __restrict__ dst, const int* __restrict__ hist,
    const int* __restrict__ bstart, int2* __restrict__ ebuf, int E, int nbuck) {
  __shared__ int cur[512];
  for (int i = threadIdx.x; i < nbuck; i += 256)
    cur[i] = bstart[i] + hist[(size_t)blockIdx.x * nbuck + i];
  __syncthreads();
  int base = blockIdx.x * CHUNK;
  int lim = base + CHUNK < E ? base + CHUNK : E;
  for (int i = base + threadIdx.x; i < lim; i += 256) {
    int d = dst[i];
    int pos = atomicAdd(&cur[d >> BSH], 1);
    ebuf[pos] = make_int2(src[i], d);
  }
}

// ---- 5. per-bucket LDS counting sort -> csr, rowptr, dinv ----
__global__ __launch_bounds__(256) void k_csr(const int2* __restrict__ ebuf,
    const int* __restrict__ bstart, int* __restrict__ csr, int* __restrict__ rowptr,
    float* __restrict__ dinv, int N, int E, int nbuck) {
  int b = blockIdx.x, t = threadIdx.x;
  int beg = bstart[b], end = bstart[b + 1];
  __shared__ int s[256];
  __shared__ int cur[256];
  s[t] = 0;
  __syncthreads();
  for (int i = beg + t; i < end; i += 256)
    atomicAdd(&s[ebuf[i].y & 255], 1);
  __syncthreads();
  int cnt = s[t];
  for (int off = 1; off < 256; off <<= 1) {  // inclusive scan
    int a = (t >= off) ? s[t - off] : 0;
    __syncthreads();
    s[t] += a;
    __syncthreads();
  }
  int ex = t ? s[t - 1] : 0;
  cur[t] = beg + ex;
  int node = (b << BSH) + t;
  if (node < N) {
    rowptr[node] = beg + ex;
    dinv[node] = rsqrtf((float)cnt + 1.0f);  // +1 self-loop
  }
  if (b == 0 && t == 0) rowptr[N] = E;
  __syncthreads();
  for (int i = beg + t; i < end; i += 256) {
    int2 e = ebuf[i];
    int pos = atomicAdd(&cur[e.y & 255], 1);
    csr[pos] = e.x;
  }
}

// ---- 0b. W1 [256][64] fp32 -> W1hT [64][256] fp16 (once, 1 block) ----
__global__ __launch_bounds__(256) void k_wcast(const float* __restrict__ W1,
    _Float16* __restrict__ whT) {
  const int t = threadIdx.x;
  const int d = t & 63;
  const int kb = (t >> 6) * 64;
  for (int i = 0; i < 8; ++i) {
    int k = kb + i * 8;
    half8 v;
#pragma unroll
    for (int j = 0; j < 8; ++j) v[j] = (_Float16)W1[(size_t)(k + j) * 64 + d];
    *(half8*)(whT + (size_t)d * 256 + k) = v;
  }
}

// ---- GEMM1 via MFMA f16: wave = 16 rows x 64 cols, K=256; all x loads hoisted ----
// h1h = fp16((x@W1)*dinv[row])
__global__ __launch_bounds__(256) void k_gemm1(const float* __restrict__ x,
    const _Float16* __restrict__ whT, const float* __restrict__ dinv,
    __half* __restrict__ h1h, int N) {
  const int l = threadIdx.x & 63;
  const int wid = threadIdx.x >> 6;
  const int r0 = (blockIdx.x * 4 + wid) * 16;
  if (r0 >= N) return;
  const int c0 = l & 15;
  const int q = l >> 4;
  const int arow = r0 + c0;
  const float* xp = x + (size_t)arow * 256 + q * 8;
  // hoist ALL x loads: 16 outstanding dwordx4 per lane (64 VGPR)
  float4 xv[8][2];
#pragma unroll
  for (int step = 0; step < 8; ++step) {
    xv[step][0] = *(const float4*)(xp + step * 32);
    xv[step][1] = *(const float4*)(xp + step * 32 + 4);
  }
  f32x4 acc0 = {0.f, 0.f, 0.f, 0.f}, acc1 = {0.f, 0.f, 0.f, 0.f};
  f32x4 acc2 = {0.f, 0.f, 0.f, 0.f}, acc3 = {0.f, 0.f, 0.f, 0.f};
#pragma unroll
  for (int step = 0; step < 8; ++step) {
    const int kb = step * 32 + q * 8;
    half8 aF;
    aF[0] = (_Float16)xv[step][0].x; aF[1] = (_Float16)xv[step][0].y;
    aF[2] = (_Float16)xv[step][0].z; aF[3] = (_Float16)xv[step][0].w;
    aF[4] = (_Float16)xv[step][1].x; aF[5] = (_Float16)xv[step][1].y;
    aF[6] = (_Float16)xv[step][1].z; aF[7] = (_Float16)xv[step][1].w;
    half8 b0 = *(const half8*)(whT + (size_t)(c0)      * 256 + kb);
    half8 b1 = *(const half8*)(whT + (size_t)(c0 + 16) * 256 + kb);
    half8 b2 = *(const half8*)(whT + (size_t)(c0 + 32) * 256 + kb);
    half8 b3 = *(const half8*)(whT + (size_t)(c0 + 48) * 256 + kb);
    acc0 = __builtin_amdgcn_mfma_f32_16x16x32_f16(aF, b0, acc0, 0, 0, 0);
    acc1 = __builtin_amdgcn_mfma_f32_16x16x32_f16(aF, b1, acc1, 0, 0, 0);
    acc2 = __builtin_amdgcn_mfma_f32_16x16x32_f16(aF, b2, acc2, 0, 0, 0);
    acc3 = __builtin_amdgcn_mfma_f32_16x16x32_f16(aF, b3, acc3, 0, 0, 0);
  }
  // C/D: col = lane&15 (+16n), row = (lane>>4)*4 + j
#pragma unroll
  for (int j = 0; j < 4; ++j) {
    int row = r0 + q * 4 + j;
    float dv = dinv[row];
    __half* ph = h1h + (size_t)row * 64 + c0;
    ph[0]  = __float2half(acc0[j] * dv);
    ph[16] = __float2half(acc1[j] * dv);
    ph[32] = __float2half(acc2[j] * dv);
    ph[48] = __float2half(acc3[j] * dv);
  }
}

#define HADD(S, HPTR, W) { \
    uint2 u_ = *(const uint2*)((HPTR) + ((size_t)(S) * (W) + r * 4)); \
    union { unsigned v; __half2 h; } c0_, c1_; c0_.v = u_.x; c1_.v = u_.y; \
    float2 f0_ = __half22float2(c0_.h), f1_ = __half22float2(c1_.h); \
    acc.x += f0_.x; acc.y += f0_.y; acc.z += f1_.x; acc.w += f1_.y; }

// ---- agg1: node per quarter-wave; fp16 gathers incl. self; fp32 accum (HID=64) ----
__global__ __launch_bounds__(256) void k_agg1f(const __half* __restrict__ h1h,
    const int* __restrict__ rowptr, const int* __restrict__ csr,
    const float* __restrict__ dinv, const float* __restrict__ b1,
    float* __restrict__ hrelu, int N) {
  const int t = threadIdx.x;
  const int r = t & 15;
  const int qq = (t >> 4) & 3;
  const int row = blockIdx.x * 16 + (t >> 4);
  if (row >= N) return;
  const int beg = rowptr[row], end = rowptr[row + 1];
  float4 acc = make_float4(0.f, 0.f, 0.f, 0.f);
  HADD(row, h1h, 64);  // self term
  for (int b = beg; b < end; b += 16) {
    int m = end - b; if (m > 16) m = 16;
    int idx = (r < m) ? csr[b + r] : 0;
    int tt = 0;
    for (; tt + 4 <= m; tt += 4) {
      int s0 = __shfl(idx, qq * 16 + tt + 0);
      int s1 = __shfl(idx, qq * 16 + tt + 1);
      int s2 = __shfl(idx, qq * 16 + tt + 2);
      int s3 = __shfl(idx, qq * 16 + tt + 3);
      HADD(s0, h1h, 64); HADD(s1, h1h, 64);
      HADD(s2, h1h, 64); HADD(s3, h1h, 64);
    }
    for (; tt < m; ++tt) {
      int s0 = __shfl(idx, qq * 16 + tt);
      HADD(s0, h1h, 64);
    }
  }
  float4 bb = *(const float4*)(b1 + r * 4);
  float dv = dinv[row];
  float4 o;
  o.x = fmaxf(dv * acc.x + bb.x, 0.f);
  o.y = fmaxf(dv * acc.y + bb.y, 0.f);
  o.z = fmaxf(dv * acc.z + bb.z, 0.f);
  o.w = fmaxf(dv * acc.w + bb.w, 0.f);
  *(float4*)(hrelu + (size_t)row * 64 + r * 4) = o;
}

// ---- GEMM2: h2h = fp16((hrelu@W2)*dinv[row]) ----
__global__ __launch_bounds__(256) void k_gemm2(const float* __restrict__ hrelu,
    const float* __restrict__ W2, const float* __restrict__ dinv,
    __half* __restrict__ h2h, int N) {
  const int lane = threadIdx.x & 63;
  const int wid = threadIdx.x >> 6;
  const int l2 = lane < 40 ? lane : 0;
  float w[64];
#pragma unroll
  for (int t = 0; t < 64; ++t) w[t] = W2[t * 40 + l2];
  for (int row = blockIdx.x * 4 + wid; row < N; row += gridDim.x * 4) {
    float xv = hrelu[(size_t)row * 64 + lane];
    float a0 = 0.f, a1 = 0.f, a2 = 0.f, a3 = 0.f;
#pragma unroll
    for (int t = 0; t < 16; ++t) {
      a0 += rl(xv, 4 * t + 0) * w[4 * t + 0];
      a1 += rl(xv, 4 * t + 1) * w[4 * t + 1];
      a2 += rl(xv, 4 * t + 2) * w[4 * t + 2];
      a3 += rl(xv, 4 * t + 3) * w[4 * t + 3];
    }
    if (lane < 40)
      h2h[(size_t)row * 40 + lane] =
          __float2half(((a0 + a1) + (a2 + a3)) * dinv[row]);
  }
}

// ---- agg2: node per quarter-wave; fp16 gathers incl. self (OUT=40) ----
__global__ __launch_bounds__(256) void k_agg2f(const __half* __restrict__ h2h,
    const int* __restrict__ rowptr, const int* __restrict__ csr,
    const float* __restrict__ dinv, const float* __restrict__ b2,
    float* __restrict__ out, int N) {
  const int t = threadIdx.x;
  const int r = t & 15;
  const int qq = (t >> 4) & 3;
  const int row = blockIdx.x * 16 + (t >> 4);
  if (row >= N) return;
  const int beg = rowptr[row], end = rowptr[row + 1];
  float4 acc = make_float4(0.f, 0.f, 0.f, 0.f);
  const bool act = (r < 10);
  if (act) HADD(row, h2h, 40);  // self term
  for (int b = beg; b < end; b += 16) {
    int m = end - b; if (m > 16) m = 16;
    int idx = (r < m) ? csr[b + r] : 0;
    int tt = 0;
    for (; tt + 4 <= m; tt += 4) {
      int s0 = __shfl(idx, qq * 16 + tt + 0);
      int s1 = __shfl(idx, qq * 16 + tt + 1);
      int s2 = __shfl(idx, qq * 16 + tt + 2);
      int s3 = __shfl(idx, qq * 16 + tt + 3);
      if (act) { HADD(s0, h2h, 40); HADD(s1, h2h, 40);
                 HADD(s2, h2h, 40); HADD(s3, h2h, 40); }
    }
    for (; tt < m; ++tt) {
      int s0 = __shfl(idx, qq * 16 + tt);
      if (act) HADD(s0, h2h, 40);
    }
  }
  if (act) {
    float4 bb = *(const float4*)(b2 + r * 4);
    float dv = dinv[row];
    float4 o;
    o.x = dv * acc.x + bb.x;
    o.y = dv * acc.y + bb.y;
    o.z = dv * acc.z + bb.z;
    o.w = dv * acc.w + bb.w;
    *(float4*)(out + (size_t)row * 40 + r * 4) = o;
  }
}

extern "C" void kernel_launch(void* const* d_in, const int* in_sizes, int n_in,
                              void* d_out, int out_size, void* d_ws, size_t ws_size,
                              hipStream_t stream) {
  const float* x  = (const float*)d_in[0];
  const int*   ei = (const int*)d_in[1];
  const float* W1 = (const float*)d_in[2];
  const float* b1 = (const float*)d_in[3];
  const float* W2 = (const float*)d_in[4];
  const float* b2 = (const float*)d_in[5];
  float* out = (float*)d_out;

  const int N = in_sizes[0] / 256;
  const int E = in_sizes[1] / 2;
  const int* src = ei;       // edge_index[0]
  const int* dst = ei + E;   // edge_index[1]

  const int nchunk = (E + CHUNK - 1) / CHUNK;
  const int nbuck  = (N + 255) >> BSH;

  // workspace layout (4B units; regions 16B-aligned)
  int* ws = (int*)d_ws;
  size_t o = 0;
  auto align4 = [](size_t v) { return (v + 3) & ~(size_t)3; };
  int* hist    = ws + o; o = align4(o + (size_t)nchunk * nbuck);
  int* colsum  = ws + o; o = align4(o + 512);
  int* bstart  = ws + o; o = align4(o + nbuck + 1);
  int* rowptr  = ws + o; o = align4(o + (size_t)N + 1);
  float* dinv  = (float*)(ws + o); o = align4(o + (size_t)N);
  int* csr     = ws + o; o = align4(o + (size_t)E);
  _Float16* whT = (_Float16*)(ws + o); o = align4(o + 64 * 256 / 2);  // 32 KB
  // region A: ebuf (E int2) then reused as h1h (N*64 half = N*32 int)
  size_t szA = (size_t)E * 2; { size_t a2 = (size_t)N * 32; if (a2 > szA) szA = a2; }
  int2*   ebuf = (int2*)(ws + o);
  __half* h1h  = (__half*)(ws + o); o = align4(o + szA);
  __half* h2h  = (__half*)(ws + o); o = align4(o + (size_t)N * 20);
  float* hrelu = (float*)(ws + o); o += (size_t)N * 64;

  k_hist    <<<nchunk, 256, 0, stream>>>(dst, hist, E, nbuck);
  k_scanA   <<<nbuck, 256, 0, stream>>>(hist, colsum, nchunk, nbuck);
  k_scanB   <<<1, 512, 0, stream>>>(colsum, bstart, nbuck, E);
  k_wcast   <<<1, 256, 0, stream>>>(W1, whT);
  k_scatter2<<<nchunk, 256, 0, stream>>>(src, dst, hist, bstart, ebuf, E, nbuck);
  k_csr     <<<nbuck, 256, 0, stream>>>(ebuf, bstart, csr, rowptr, dinv, N, E, nbuck);

  int nwave = (N + 15) / 16;
  k_gemm1<<<(nwave + 3) / 4, 256, 0, stream>>>(x, whT, dinv, h1h, N);
  k_agg1f<<<(N + 15) / 16, 256, 0, stream>>>(h1h, rowptr, csr, dinv, b1, hrelu, N);
  k_gemm2<<<2048, 256, 0, stream>>>(hrelu, W2, dinv, h2h, N);
  k_agg2f<<<(N + 15) / 16, 256, 0, stream>>>(h2h, rowptr, csr, dinv, b2, out, N);
}